// Round 1
// 492.591 us; speedup vs baseline: 1.1064x; 1.1064x over previous
//
#include <hip/hip_runtime.h>

typedef unsigned short u16;
typedef unsigned int u32;
using f32x4 = __attribute__((ext_vector_type(4))) float;
using u32x4 = __attribute__((ext_vector_type(4))) u32;
typedef u32x4 __attribute__((may_alias)) u32x4a;  // TBAA-safe 16B vector
typedef uint2 __attribute__((may_alias)) uint2a;  // TBAA-safe 8B vector
using bf16x8 = __attribute__((ext_vector_type(8))) __bf16;

#define SEQ 2048  // per batch

// fp32 -> bf16 round-to-nearest-even
__device__ __forceinline__ u16 f2bf(float f) {
  union { float f; u32 u; } c; c.f = f;
  return (u16)((c.u + 0x7fffu + ((c.u >> 16) & 1u)) >> 16);
}
__device__ __forceinline__ float bf2f(u16 h) {
  union { u32 u; float f; } c; c.u = ((u32)h) << 16;
  return c.f;
}
__device__ __forceinline__ bf16x8 ld16(const u16* p) {
  return __builtin_bit_cast(bf16x8, *(const u32x4a*)p);
}
__device__ __forceinline__ f32x4 mfma16(bf16x8 a, bf16x8 b, f32x4 c) {
  return __builtin_amdgcn_mfma_f32_16x16x32_bf16(a, b, c, 0, 0, 0);
}
// async global->LDS, 16B/lane; LDS dest = wave-uniform base + lane*16
__device__ __forceinline__ void gload_lds16(const u16* g, u16* l) {
  __builtin_amdgcn_global_load_lds(
      (const __attribute__((address_space(1))) void*)g,
      (__attribute__((address_space(3))) void*)l, 16, 0, 0);
}
// pack 2 fp32 -> 1 u32 of 2 bf16 (RNE); no builtin on gfx950
__device__ __forceinline__ u32 cvtpk(float lo, float hi) {
  u32 r;
  asm("v_cvt_pk_bf16_f32 %0, %1, %2" : "=v"(r) : "v"(lo), "v"(hi));
  return r;
}
// new_a = [a.lanes0-31 | b.lanes0-31], new_b = [a.lanes32-63 | b.lanes32-63]
__device__ __forceinline__ void plane32_swap(u32& a, u32& b) {
  asm("v_permlane32_swap_b32 %0, %1" : "+v"(a), "+v"(b));
}
__device__ __forceinline__ f32x4 vmax4(f32x4 a, f32x4 b) {
  f32x4 r;
  r[0] = fmaxf(a[0], b[0]); r[1] = fmaxf(a[1], b[1]);
  r[2] = fmaxf(a[2], b[2]); r[3] = fmaxf(a[3], b[3]);
  return r;
}

// ---------------- input dtype detection ----------------
__global__ void detect_dtype(const u16* __restrict__ x, int* __restrict__ flag) {
  if (threadIdx.x == 0) {
    int cnt = 0;
    for (int i = 0; i < 32; ++i) {
      const int e = (x[2 * i] >> 7) & 0xFF;
      cnt += (e >= 100 && e <= 140) ? 1 : 0;
    }
    *flag = (cnt >= 20) ? 1 : 0;  // 1 = inputs are bf16
  }
}

// ---------------- prep kernels ----------------

__global__ __launch_bounds__(256)
void cvt_x(const void* __restrict__ in, u16* __restrict__ out,
           const int* __restrict__ flag, size_t eoff4) {
  const size_t i = (size_t)blockIdx.x * 256 + threadIdx.x;
  if (*flag) {
    ((uint2*)out)[i] = ((const uint2*)in)[eoff4 + i];
  } else {
    const float4 v = ((const float4*)in)[eoff4 + i];
    uint2 ov;
    ov.x = (u32)f2bf(v.x) | ((u32)f2bf(v.y) << 16);
    ov.y = (u32)f2bf(v.z) | ((u32)f2bf(v.w) << 16);
    ((uint2*)out)[i] = ov;
  }
}

__global__ __launch_bounds__(256)
void cvt_bias(const void* __restrict__ in, float* __restrict__ out, int n,
              const int* __restrict__ flag) {
  const int i = blockIdx.x * 256 + threadIdx.x;
  if (i >= n) return;
  out[i] = (*flag) ? bf2f(((const u16*)in)[i]) : ((const float*)in)[i];
}

// in [K,N] (fp32 or bf16) -> out bf16 [N,K]. 64x64 tiles via LDS.
__global__ __launch_bounds__(256)
void transpose_w(const void* __restrict__ in, u16* __restrict__ out, int K, int N,
                 const int* __restrict__ flag) {
  __shared__ float t[64][65];
  const int tid = threadIdx.x;
  const int r = tid >> 4, c4 = tid & 15;
  const int n0 = blockIdx.x << 6, k0 = blockIdx.y << 6;
  const int fl = *flag;
#pragma unroll
  for (int i = 0; i < 4; ++i) {
    const int kk = r + i * 16;
    const size_t base = (size_t)(k0 + kk) * N + n0 + c4 * 4;
    if (fl) {
      const uint2 raw = *(const uint2*)((const u16*)in + base);
      t[kk][c4 * 4 + 0] = bf2f((u16)(raw.x & 0xFFFF));
      t[kk][c4 * 4 + 1] = bf2f((u16)(raw.x >> 16));
      t[kk][c4 * 4 + 2] = bf2f((u16)(raw.y & 0xFFFF));
      t[kk][c4 * 4 + 3] = bf2f((u16)(raw.y >> 16));
    } else {
      const float4 v = *(const float4*)((const float*)in + base);
      t[kk][c4 * 4 + 0] = v.x; t[kk][c4 * 4 + 1] = v.y;
      t[kk][c4 * 4 + 2] = v.z; t[kk][c4 * 4 + 3] = v.w;
    }
  }
  __syncthreads();
#pragma unroll
  for (int i = 0; i < 4; ++i) {
    const int nn = r + i * 16;
    uint2 ov;
    ov.x = (u32)f2bf(t[c4 * 4 + 0][nn]) | ((u32)f2bf(t[c4 * 4 + 1][nn]) << 16);
    ov.y = (u32)f2bf(t[c4 * 4 + 2][nn]) | ((u32)f2bf(t[c4 * 4 + 3][nn]) << 16);
    *(uint2*)&out[(size_t)(n0 + nn) * K + k0 + c4 * 4] = ov;
  }
}

// qkv bf16 [nb*2048, 3072] (V cols 2048..3071) -> vt [nb*16][d=64][s=2048]
__global__ __launch_bounds__(256)
void transpose_v(const u16* __restrict__ qkv, u16* __restrict__ vt) {
  __shared__ __align__(16) u16 t[64][72];
  const int h = blockIdx.x, s0 = blockIdx.y << 6, b = blockIdx.z;
  const int tid = threadIdx.x;
  const int r = tid >> 2, g = tid & 3;
  const u16* src = &qkv[(size_t)(b * SEQ + s0 + r) * 3072 + 2048 + h * 64 + g * 16];
  *(u32x4a*)&t[r][g * 16]     = *(const u32x4a*)src;
  *(u32x4a*)&t[r][g * 16 + 8] = *(const u32x4a*)(src + 8);
  __syncthreads();
  union { u16 s[16]; u32x4 v[2]; } u;
#pragma unroll
  for (int e = 0; e < 16; ++e) u.s[e] = t[g * 16 + e][r];
  u16* dst = &vt[(size_t)((b * 16 + h) * 64 + r) * 2048 + s0 + g * 16];
  *(u32x4a*)dst = u.v[0];
  *(u32x4a*)(dst + 8) = u.v[1];
}

// ---------------- GEMM: C[M,N] = A[M,K]*BT[N,K]^T + bias ----------------
// 128x128 tile, BK=32, 4 waves 2x2, m97-style global_load_lds staging.
template <bool BF16_OUT>
__global__ __launch_bounds__(256)
void gemm_bt(const u16* __restrict__ A, const u16* __restrict__ BT,
             const float* __restrict__ bias, void* __restrict__ Cv,
             int M, int N, int K) {
  constexpr int BK = 32;
  __shared__ __align__(16) u16 lA[128 * BK];
  __shared__ __align__(16) u16 lB[128 * BK];
  const int tid = threadIdx.x;
  const int wid = tid >> 6, lane = tid & 63;
  const int quad = lane >> 4, l16 = lane & 15;
  const int tile_m = blockIdx.y << 7, tile_n = blockIdx.x << 7;
  const int wm = (wid >> 1) << 6, wn = (wid & 1) << 6;
  const int G0 = wid * 64 + lane, G1 = G0 + 256;
  const int r0 = G0 >> 2, c0 = (G0 & 3) * 8;
  const int r1 = G1 >> 2, c1 = (G1 & 3) * 8;
  u16* const dA0 = lA + wid * 512;
  u16* const dA1 = lA + 2048 + wid * 512;
  u16* const dB0 = lB + wid * 512;
  u16* const dB1 = lB + 2048 + wid * 512;

  f32x4 acc[4][4] = {};

  for (int k0 = 0; k0 < K; k0 += BK) {
    __syncthreads();
    gload_lds16(&A [(size_t)(tile_m + r0) * K + k0 + c0], dA0);
    gload_lds16(&BT[(size_t)(tile_n + r0) * K + k0 + c0], dB0);
    gload_lds16(&A [(size_t)(tile_m + r1) * K + k0 + c1], dA1);
    gload_lds16(&BT[(size_t)(tile_n + r1) * K + k0 + c1], dB1);
    __syncthreads();
    bf16x8 af[4], bfr[4];
#pragma unroll
    for (int i = 0; i < 4; ++i) {
      af[i]  = ld16(&lA[(wm + i * 16 + l16) * BK + quad * 8]);
      bfr[i] = ld16(&lB[(wn + i * 16 + l16) * BK + quad * 8]);
    }
#pragma unroll
    for (int i = 0; i < 4; ++i)
#pragma unroll
      for (int j = 0; j < 4; ++j) acc[i][j] = mfma16(af[i], bfr[j], acc[i][j]);
  }

#pragma unroll
  for (int j = 0; j < 4; ++j) {
    const int cg = tile_n + wn + j * 16 + l16;
    const float bv = bias[cg];
#pragma unroll
    for (int i = 0; i < 4; ++i) {
      const int rg = tile_m + wm + i * 16 + quad * 4;
#pragma unroll
      for (int r = 0; r < 4; ++r) {
        const float v = acc[i][j][r] + bv;
        if constexpr (BF16_OUT)
          ((u16*)Cv)[(size_t)(rg + r) * N + cg] = f2bf(v);
        else
          ((float*)Cv)[(size_t)(rg + r) * N + cg] = v;
      }
    }
  }
}

// ---------------- causal flash attention (swapped-QK, in-register P) -----
// grid (16 h, 16 pair-slots, nb). Block y processes q-tiles {31-y, y}:
// uniform 33 k-tile iterations per wave -> no causal tail imbalance.
// Wave w owns q rows qt*64+w*16..+15 of the current tile.
//
// QK^T computed SWAPPED: mfma(A=K, B=Q) -> S^T[k][q]; lane (quad Q, l16=q)
// holds k = f*16+Q*4+r for ONE q. Softmax row-reduce = in-register tree +
// shfl_xor(16) + shfl_xor(32). P converted to bf16 via v_cvt_pk_bf16_f32 and
// redistributed to the PV B-fragment layout (k=Q*8+e, n=q=l16) entirely in
// registers: v_permlane32_swap (quads {0,1}<->{2,3}) + one shfl_xor(16) per
// half + cndmask selects (verified vs C/D maps: col=lane&15, row=quad*4+r).
// PV computes O^T = mfma(A=V^T, B=P^T) so alpha/l state stays lane-aligned;
// epilogue transposes 16x64 per wave through LDS for coalesced stores.
__global__ __launch_bounds__(256, 4)
void attn_fwd(const u16* __restrict__ qkv, const u16* __restrict__ vt,
              u16* __restrict__ aout) {
  const int h = blockIdx.x, b = blockIdx.z;
  const int tid = threadIdx.x, wid = tid >> 6, lane = tid & 63;
  const int quad = lane >> 4, l16 = lane & 15;
  const int qodd = quad & 1;
  __shared__ __align__(16) u16 lT[4][16][72];  // per-wave transpose buffer

  const f32x4 z = {0.f, 0.f, 0.f, 0.f};
  // loop-invariant bases (row l16; advance 64 rows (K) / 64 cols (V) per kt)
  const u16* const kbase_p =
      qkv + (size_t)(b * SEQ + l16) * 3072 + 1024 + h * 64 + quad * 8;
  const u16* const vbase_p =
      vt + (size_t)((b * 16 + h) * 64 + l16) * 2048 + quad * 8;

#pragma unroll 1
  for (int pass = 0; pass < 2; ++pass) {
    const int qt = pass ? blockIdx.y : 31 - blockIdx.y;
    const int q0 = qt * 64 + wid * 16;
    // Q fragment (B operand): rows q=l16, d cols quad*8+{0..7}, +32
    const size_t qi = (size_t)(b * SEQ + q0 + l16) * 3072 + h * 64 + quad * 8;
    const bf16x8 aq0 = ld16(&qkv[qi]);
    const bf16x8 aq1 = ld16(&qkv[qi + 32]);
    f32x4 o[4] = {z, z, z, z};
    float m_r = -1e30f, l_r = 0.f;
    const u16* kp = kbase_p;
    const u16* vp = vbase_p;

    for (int kt = 0; kt <= qt; ++kt, kp += 64 * 3072, vp += 64) {
      // S^T[k][q]: k = f*16 + quad*4 + r, q = l16
      f32x4 s[4];
#pragma unroll
      for (int f = 0; f < 4; ++f) {
        const u16* kf = kp + (size_t)f * 16 * 3072;
        f32x4 a = z;
        a = mfma16(ld16(kf), aq0, a);
        a = mfma16(ld16(kf + 32), aq1, a);
        s[f] = a * 0.125f;  // 1/sqrt(64)
      }
      // V^T fragments (A operand: rows d=f*16+l16, k-cols quad*8+e), issued
      // early so global latency hides under softmax.
      bf16x8 vf0[4], vf1[4];
#pragma unroll
      for (int f = 0; f < 4; ++f) {
        const u16* vv = vp + (size_t)f * 16 * 2048;
        vf0[f] = ld16(vv);
        vf1[f] = ld16(vv + 32);
      }
      if (kt == qt) {  // diagonal tile: mask k_local > q_local
#pragma unroll
        for (int f = 0; f < 4; ++f)
#pragma unroll
          for (int r = 0; r < 4; ++r)
            if (f * 16 + quad * 4 + r > wid * 16 + l16) s[f][r] = -1e30f;
      }
      // row max over 64 k: 16 in-register + 2 cross-quad shuffles
      const f32x4 m4 = vmax4(vmax4(s[0], s[1]), vmax4(s[2], s[3]));
      float mm = fmaxf(fmaxf(m4[0], m4[1]), fmaxf(m4[2], m4[3]));
      mm = fmaxf(mm, __shfl_xor(mm, 16));
      mm = fmaxf(mm, __shfl_xor(mm, 32));
      const float mn = fmaxf(m_r, mm);
      const float alpha = __expf(m_r - mn);
      m_r = mn;
      // p = exp(s - m), in place
#pragma unroll
      for (int f = 0; f < 4; ++f)
#pragma unroll
        for (int r = 0; r < 4; ++r) s[f][r] = __expf(s[f][r] - mn);
      const f32x4 s4 = (s[0] + s[1]) + (s[2] + s[3]);
      float sv = (s4[0] + s4[1]) + (s4[2] + s4[3]);
      sv += __shfl_xor(sv, 16);
      sv += __shfl_xor(sv, 32);
      l_r = l_r * alpha + sv;
#pragma unroll
      for (int f = 0; f < 4; ++f)
#pragma unroll
        for (int r = 0; r < 4; ++r) o[f][r] *= alpha;
      // pack P pairs: u[f][j] = {p[f][2j], p[f][2j+1]} (k = f*16+quad*4+2j+{0,1})
      u32 u00 = cvtpk(s[0][0], s[0][1]), u01 = cvtpk(s[0][2], s[0][3]);
      u32 u10 = cvtpk(s[1][0], s[1][1]), u11 = cvtpk(s[1][2], s[1][3]);
      u32 u20 = cvtpk(s[2][0], s[2][1]), u21 = cvtpk(s[2][2], s[2][3]);
      u32 u30 = cvtpk(s[3][0], s[3][1]), u31 = cvtpk(s[3][2], s[3][3]);
      // exchange -> B-fragment P0 (k in [0,32)) and P1 (k in [32,64))
      u32x4 P0, P1;
      {
        u32 A0 = u00, B0 = u10, A1 = u01, B1 = u11;
        plane32_swap(A0, B0);  // A=[u00@Q01|u10@Q01], B=[u00@Q23|u10@Q23]
        plane32_swap(A1, B1);
        u32 Y0 = qodd ? A0 : B0;
        u32 Y1 = qodd ? A1 : B1;
        Y0 = (u32)__shfl_xor((int)Y0, 16);
        Y1 = (u32)__shfl_xor((int)Y1, 16);
        P0[0] = qodd ? Y0 : A0;
        P0[1] = qodd ? Y1 : A1;
        P0[2] = qodd ? B0 : Y0;
        P0[3] = qodd ? B1 : Y1;
      }
      {
        u32 A0 = u20, B0 = u30, A1 = u21, B1 = u31;
        plane32_swap(A0, B0);
        plane32_swap(A1, B1);
        u32 Y0 = qodd ? A0 : B0;
        u32 Y1 = qodd ? A1 : B1;
        Y0 = (u32)__shfl_xor((int)Y0, 16);
        Y1 = (u32)__shfl_xor((int)Y1, 16);
        P1[0] = qodd ? Y0 : A0;
        P1[1] = qodd ? Y1 : A1;
        P1[2] = qodd ? B0 : Y0;
        P1[3] = qodd ? B1 : Y1;
      }
      const bf16x8 pb0 = __builtin_bit_cast(bf16x8, P0);
      const bf16x8 pb1 = __builtin_bit_cast(bf16x8, P1);
      // O^T[d][q] += V^T * P^T
#pragma unroll
      for (int f = 0; f < 4; ++f) {
        o[f] = mfma16(vf0[f], pb0, o[f]);
        o[f] = mfma16(vf1[f], pb1, o[f]);
      }
    }
    // epilogue: o[f][r] = O^T[d=f*16+quad*4+r][q=l16]; transpose via LDS.
    const float inv = 1.0f / l_r;
#pragma unroll
    for (int f = 0; f < 4; ++f) {
      uint2a wv;
      wv.x = cvtpk(o[f][0] * inv, o[f][1] * inv);
      wv.y = cvtpk(o[f][2] * inv, o[f][3] * inv);
      *(uint2a*)&lT[wid][l16][f * 16 + quad * 4] = wv;
    }
    // same-wave DS ordering: no barrier needed (wave-private slice)
    const int row = lane >> 2, cg = (lane & 3) * 16;
    union { uint2a d2[4]; u32x4 d4[2]; } g;
    g.d2[0] = *(const uint2a*)&lT[wid][row][cg];
    g.d2[1] = *(const uint2a*)&lT[wid][row][cg + 4];
    g.d2[2] = *(const uint2a*)&lT[wid][row][cg + 8];
    g.d2[3] = *(const uint2a*)&lT[wid][row][cg + 12];
    u16* dst = &aout[(size_t)(b * SEQ + q0 + row) * 1024 + h * 64 + cg];
    *(u32x4a*)dst = g.d4[0];
    *(u32x4a*)(dst + 8) = g.d4[1];
  }
}

extern "C" void kernel_launch(void* const* d_in, const int* in_sizes, int n_in,
                              void* d_out, int out_size, void* d_ws, size_t ws_size,
                              hipStream_t stream) {
  const void* x     = d_in[0];
  const void* w_qkv = d_in[1];
  const void* b_qkv = d_in[2];
  const void* w_out = d_in[3];
  const void* b_out = d_in[4];
  float* out = (float*)d_out;  // reference output dtype is fp32

  // common prefix
  float* bqf   = (float*)d_ws;                      // [3072] fp32
  float* bof   = bqf + 3072;                        // [1024] fp32
  int*   flag  = (int*)(bof + 1024);                // [4]
  u16*   wqkvT = (u16*)(flag + 4);                  // [3072,1024]
  u16*   woutT = wqkvT + (size_t)3072 * 1024;       // [1024,1024]
  u16*   xb    = woutT + (size_t)1024 * 1024;       // [M,1024]

  detect_dtype<<<dim3(1), dim3(64), 0, stream>>>((const u16*)x, flag);
  cvt_bias<<<dim3(12), dim3(256), 0, stream>>>(b_qkv, bqf, 3072, flag);
  cvt_bias<<<dim3(4), dim3(256), 0, stream>>>(b_out, bof, 1024, flag);
  transpose_w<<<dim3(48, 16), dim3(256), 0, stream>>>(w_qkv, wqkvT, 1024, 3072, flag);
  transpose_w<<<dim3(16, 16), dim3(256), 0, stream>>>(w_out, woutT, 1024, 1024, flag);

  // full-batch path needs 92,291,088 B of ws; fall back to per-batch otherwise.
  const size_t FULL_WS = 92291088;  // constant across calls -> graph-safe branch
  if (ws_size >= FULL_WS) {
    u16* qkv = xb  + (size_t)8192 * 1024;           // [8192,3072]
    u16* vt  = qkv + (size_t)8192 * 3072;           // [64,64,2048]
    cvt_x<<<dim3(8192), dim3(256), 0, stream>>>(x, xb, flag, 0);
    gemm_bt<true ><<<dim3(24, 64), dim3(256), 0, stream>>>(xb, wqkvT, bqf, qkv,
                                                           8192, 3072, 1024);
    transpose_v<<<dim3(16, 32, 4), dim3(256), 0, stream>>>(qkv, vt);
    attn_fwd<<<dim3(16, 16, 4), dim3(256), 0, stream>>>(qkv, vt, xb);
    gemm_bt<false><<<dim3(8, 64), dim3(256), 0, stream>>>(xb, woutT, bof, out,
                                                          8192, 1024, 1024);
  } else {
    u16* qkvb = xb   + (size_t)2048 * 1024;         // [2048,3072]
    u16* vtb  = qkvb + (size_t)2048 * 3072;         // [16,64,2048]
    for (int b = 0; b < 4; ++b) {
      const size_t eoff4 = (size_t)b * 2048 * 1024 / 4;
      cvt_x<<<dim3(2048), dim3(256), 0, stream>>>(x, xb, flag, eoff4);
      gemm_bt<true ><<<dim3(24, 16), dim3(256), 0, stream>>>(xb, wqkvT, bqf, qkvb,
                                                             2048, 3072, 1024);
      transpose_v<<<dim3(16, 32, 1), dim3(256), 0, stream>>>(qkvb, vtb);
      attn_fwd<<<dim3(16, 16, 1), dim3(256), 0, stream>>>(qkvb, vtb, xb);
      gemm_bt<false><<<dim3(8, 16), dim3(256), 0, stream>>>(
          xb, woutT, bof, out + (size_t)b * 2048 * 1024, 2048, 1024, 1024);
    }
  }
}

// Round 2
// 333.481 us; speedup vs baseline: 1.6343x; 1.4771x over previous
//
#include <hip/hip_runtime.h>

typedef unsigned short u16;
typedef unsigned int u32;
using f32x4 = __attribute__((ext_vector_type(4))) float;
using u32x4 = __attribute__((ext_vector_type(4))) u32;
typedef u32x4 __attribute__((may_alias)) u32x4a;  // TBAA-safe 16B vector
typedef uint2 __attribute__((may_alias)) uint2a;  // TBAA-safe 8B vector
using bf16x8 = __attribute__((ext_vector_type(8))) __bf16;

#define SEQ 2048  // per batch

// fp32 -> bf16 round-to-nearest-even
__device__ __forceinline__ u16 f2bf(float f) {
  union { float f; u32 u; } c; c.f = f;
  return (u16)((c.u + 0x7fffu + ((c.u >> 16) & 1u)) >> 16);
}
__device__ __forceinline__ float bf2f(u16 h) {
  union { u32 u; float f; } c; c.u = ((u32)h) << 16;
  return c.f;
}
__device__ __forceinline__ bf16x8 ld16(const u16* p) {
  return __builtin_bit_cast(bf16x8, *(const u32x4a*)p);
}
__device__ __forceinline__ f32x4 mfma16(bf16x8 a, bf16x8 b, f32x4 c) {
  return __builtin_amdgcn_mfma_f32_16x16x32_bf16(a, b, c, 0, 0, 0);
}
// async global->LDS, 16B/lane; LDS dest = wave-uniform base + lane*16
__device__ __forceinline__ void gload_lds16(const u16* g, u16* l) {
  __builtin_amdgcn_global_load_lds(
      (const __attribute__((address_space(1))) void*)g,
      (__attribute__((address_space(3))) void*)l, 16, 0, 0);
}
// pack 2 fp32 -> 1 u32 of 2 bf16 (RNE); no builtin on gfx950
__device__ __forceinline__ u32 cvtpk(float lo, float hi) {
  u32 r;
  asm("v_cvt_pk_bf16_f32 %0, %1, %2" : "=v"(r) : "v"(lo), "v"(hi));
  return r;
}
// new_a = [a.lanes0-31 | b.lanes0-31], new_b = [a.lanes32-63 | b.lanes32-63]
__device__ __forceinline__ void plane32_swap(u32& a, u32& b) {
  asm("v_permlane32_swap_b32 %0, %1" : "+v"(a), "+v"(b));
}
__device__ __forceinline__ f32x4 vmax4(f32x4 a, f32x4 b) {
  f32x4 r;
  r[0] = fmaxf(a[0], b[0]); r[1] = fmaxf(a[1], b[1]);
  r[2] = fmaxf(a[2], b[2]); r[3] = fmaxf(a[3], b[3]);
  return r;
}

// ---------------- input dtype detection ----------------
__global__ void detect_dtype(const u16* __restrict__ x, int* __restrict__ flag) {
  if (threadIdx.x == 0) {
    int cnt = 0;
    for (int i = 0; i < 32; ++i) {
      const int e = (x[2 * i] >> 7) & 0xFF;
      cnt += (e >= 100 && e <= 140) ? 1 : 0;
    }
    *flag = (cnt >= 20) ? 1 : 0;  // 1 = inputs are bf16
  }
}

// ---------------- prep kernels ----------------

__global__ __launch_bounds__(256)
void cvt_x(const void* __restrict__ in, u16* __restrict__ out,
           const int* __restrict__ flag, size_t eoff4) {
  const size_t i = (size_t)blockIdx.x * 256 + threadIdx.x;
  if (*flag) {
    ((uint2*)out)[i] = ((const uint2*)in)[eoff4 + i];
  } else {
    const float4 v = ((const float4*)in)[eoff4 + i];
    uint2 ov;
    ov.x = (u32)f2bf(v.x) | ((u32)f2bf(v.y) << 16);
    ov.y = (u32)f2bf(v.z) | ((u32)f2bf(v.w) << 16);
    ((uint2*)out)[i] = ov;
  }
}

__global__ __launch_bounds__(256)
void cvt_bias(const void* __restrict__ in, float* __restrict__ out, int n,
              const int* __restrict__ flag) {
  const int i = blockIdx.x * 256 + threadIdx.x;
  if (i >= n) return;
  out[i] = (*flag) ? bf2f(((const u16*)in)[i]) : ((const float*)in)[i];
}

// in [K,N] (fp32 or bf16) -> out bf16 [N,K]. 64x64 tiles via LDS.
__global__ __launch_bounds__(256)
void transpose_w(const void* __restrict__ in, u16* __restrict__ out, int K, int N,
                 const int* __restrict__ flag) {
  __shared__ float t[64][65];
  const int tid = threadIdx.x;
  const int r = tid >> 4, c4 = tid & 15;
  const int n0 = blockIdx.x << 6, k0 = blockIdx.y << 6;
  const int fl = *flag;
#pragma unroll
  for (int i = 0; i < 4; ++i) {
    const int kk = r + i * 16;
    const size_t base = (size_t)(k0 + kk) * N + n0 + c4 * 4;
    if (fl) {
      const uint2 raw = *(const uint2*)((const u16*)in + base);
      t[kk][c4 * 4 + 0] = bf2f((u16)(raw.x & 0xFFFF));
      t[kk][c4 * 4 + 1] = bf2f((u16)(raw.x >> 16));
      t[kk][c4 * 4 + 2] = bf2f((u16)(raw.y & 0xFFFF));
      t[kk][c4 * 4 + 3] = bf2f((u16)(raw.y >> 16));
    } else {
      const float4 v = *(const float4*)((const float*)in + base);
      t[kk][c4 * 4 + 0] = v.x; t[kk][c4 * 4 + 1] = v.y;
      t[kk][c4 * 4 + 2] = v.z; t[kk][c4 * 4 + 3] = v.w;
    }
  }
  __syncthreads();
#pragma unroll
  for (int i = 0; i < 4; ++i) {
    const int nn = r + i * 16;
    uint2 ov;
    ov.x = (u32)f2bf(t[c4 * 4 + 0][nn]) | ((u32)f2bf(t[c4 * 4 + 1][nn]) << 16);
    ov.y = (u32)f2bf(t[c4 * 4 + 2][nn]) | ((u32)f2bf(t[c4 * 4 + 3][nn]) << 16);
    *(uint2*)&out[(size_t)(n0 + nn) * K + k0 + c4 * 4] = ov;
  }
}

// qkv bf16 [nb*2048, 3072] (V cols 2048..3071) -> vt [nb*16][d=64][s=2048]
__global__ __launch_bounds__(256)
void transpose_v(const u16* __restrict__ qkv, u16* __restrict__ vt) {
  __shared__ __align__(16) u16 t[64][72];
  const int h = blockIdx.x, s0 = blockIdx.y << 6, b = blockIdx.z;
  const int tid = threadIdx.x;
  const int r = tid >> 2, g = tid & 3;
  const u16* src = &qkv[(size_t)(b * SEQ + s0 + r) * 3072 + 2048 + h * 64 + g * 16];
  *(u32x4a*)&t[r][g * 16]     = *(const u32x4a*)src;
  *(u32x4a*)&t[r][g * 16 + 8] = *(const u32x4a*)(src + 8);
  __syncthreads();
  union { u16 s[16]; u32x4 v[2]; } u;
#pragma unroll
  for (int e = 0; e < 16; ++e) u.s[e] = t[g * 16 + e][r];
  u16* dst = &vt[(size_t)((b * 16 + h) * 64 + r) * 2048 + s0 + g * 16];
  *(u32x4a*)dst = u.v[0];
  *(u32x4a*)(dst + 8) = u.v[1];
}

// ---------------- GEMM: C[M,N] = A[M,K]*BT[N,K]^T + bias ----------------
// 128x128 tile, BK=32, 4 waves 2x2, m97-style global_load_lds staging.
template <bool BF16_OUT>
__global__ __launch_bounds__(256)
void gemm_bt(const u16* __restrict__ A, const u16* __restrict__ BT,
             const float* __restrict__ bias, void* __restrict__ Cv,
             int M, int N, int K) {
  constexpr int BK = 32;
  __shared__ __align__(16) u16 lA[128 * BK];
  __shared__ __align__(16) u16 lB[128 * BK];
  const int tid = threadIdx.x;
  const int wid = tid >> 6, lane = tid & 63;
  const int quad = lane >> 4, l16 = lane & 15;
  const int tile_m = blockIdx.y << 7, tile_n = blockIdx.x << 7;
  const int wm = (wid >> 1) << 6, wn = (wid & 1) << 6;
  const int G0 = wid * 64 + lane, G1 = G0 + 256;
  const int r0 = G0 >> 2, c0 = (G0 & 3) * 8;
  const int r1 = G1 >> 2, c1 = (G1 & 3) * 8;
  u16* const dA0 = lA + wid * 512;
  u16* const dA1 = lA + 2048 + wid * 512;
  u16* const dB0 = lB + wid * 512;
  u16* const dB1 = lB + 2048 + wid * 512;

  f32x4 acc[4][4] = {};

  for (int k0 = 0; k0 < K; k0 += BK) {
    __syncthreads();
    gload_lds16(&A [(size_t)(tile_m + r0) * K + k0 + c0], dA0);
    gload_lds16(&BT[(size_t)(tile_n + r0) * K + k0 + c0], dB0);
    gload_lds16(&A [(size_t)(tile_m + r1) * K + k0 + c1], dA1);
    gload_lds16(&BT[(size_t)(tile_n + r1) * K + k0 + c1], dB1);
    __syncthreads();
    bf16x8 af[4], bfr[4];
#pragma unroll
    for (int i = 0; i < 4; ++i) {
      af[i]  = ld16(&lA[(wm + i * 16 + l16) * BK + quad * 8]);
      bfr[i] = ld16(&lB[(wn + i * 16 + l16) * BK + quad * 8]);
    }
#pragma unroll
    for (int i = 0; i < 4; ++i)
#pragma unroll
      for (int j = 0; j < 4; ++j) acc[i][j] = mfma16(af[i], bfr[j], acc[i][j]);
  }

#pragma unroll
  for (int j = 0; j < 4; ++j) {
    const int cg = tile_n + wn + j * 16 + l16;
    const float bv = bias[cg];
#pragma unroll
    for (int i = 0; i < 4; ++i) {
      const int rg = tile_m + wm + i * 16 + quad * 4;
#pragma unroll
      for (int r = 0; r < 4; ++r) {
        const float v = acc[i][j][r] + bv;
        if constexpr (BF16_OUT)
          ((u16*)Cv)[(size_t)(rg + r) * N + cg] = f2bf(v);
        else
          ((float*)Cv)[(size_t)(rg + r) * N + cg] = v;
      }
    }
  }
}

// ---------------- causal flash attention ----------------
// grid (16 h, 16 pair-slots, nb). Block y does q-tiles {31-y, y}: uniform 33
// k-iterations. Swapped QK (S^T), in-register softmax/P-exchange (round 1).
// NEW this round: K/V tiles staged once per BLOCK into double-buffered LDS
// via global_load_lds (was: each of 4 waves redundantly loading 16 KB/iter
// from L3 at ~700cyc exposed latency). T3-min schedule: stage(kt+1) issued at
// top of iter kt, drained by the single end-of-iter __syncthreads. T2: LDS
// rows are 128 B (16-way conflict), fixed by pre-swizzled global source col
// (slot ^ (row&7)) + same XOR on ds_read (rule #21: both-sides-or-neither).
// T13 defer-max (base-2, THR=8): common path has NO cross-lane max reduce,
// no alpha exp, no O rescale. exp2 with log2e folded into QK scale.
__global__ __launch_bounds__(256, 4)
void attn_fwd(const u16* __restrict__ qkv, const u16* __restrict__ vt,
              u16* __restrict__ aout) {
  const int h = blockIdx.x, b = blockIdx.z;
  const int tid = threadIdx.x, wid = tid >> 6, lane = tid & 63;
  const int quad = lane >> 4, l16 = lane & 15;
  const int qodd = quad & 1;
  __shared__ __align__(16) u16 lK[2][4096];  // [buf][64 rows x 64 cols]
  __shared__ __align__(16) u16 lV[2][4096];  // [buf][64 d x 64 k]

  // staging: granule G = rnd*256 + wid*64 + lane; row=G>>3, slot=G&7.
  // LDS linear (G*16B); source fetches granule col (slot ^ (row&7)).
  const int G0 = wid * 64 + lane, G1 = G0 + 256;
  const int r0 = G0 >> 3, c0 = ((G0 & 7) ^ (r0 & 7)) * 8;
  const int r1 = G1 >> 3, c1 = ((G1 & 7) ^ (r1 & 7)) * 8;
  const int db0 = wid * 512, db1 = 2048 + wid * 512;  // wave-uniform u16 offs

  const u16* const kg = qkv + (size_t)(b * SEQ) * 3072 + 1024 + h * 64;
  const u16* const vg = vt + (size_t)((b * 16 + h) * 64) * 2048;

  // swizzled read slots: logical granule col {quad, quad+4}, row-XOR l16&7
  const int sl0 = (quad ^ (l16 & 7)) * 8;
  const int sl1 = sl0 ^ 32;

  const f32x4 z = {0.f, 0.f, 0.f, 0.f};
  int cur = 0;

#pragma unroll 1
  for (int pass = 0; pass < 2; ++pass) {
    const int qt = pass ? (int)blockIdx.y : 31 - (int)blockIdx.y;
    const int q0 = qt * 64 + wid * 16;
    const size_t qi = (size_t)(b * SEQ + q0 + l16) * 3072 + h * 64 + quad * 8;
    const bf16x8 aq0 = ld16(&qkv[qi]);
    const bf16x8 aq1 = ld16(&qkv[qi + 32]);
    f32x4 o[4] = {z, z, z, z};
    float m_r = -1e30f, l_r = 0.f;

    // prologue stage of tile 0 (safe vs other waves: target buffer was last
    // read >=2 barriers ago)
    {
      gload_lds16(kg + (size_t)r0 * 3072 + c0, &lK[cur][db0]);
      gload_lds16(kg + (size_t)r1 * 3072 + c1, &lK[cur][db1]);
      gload_lds16(vg + (size_t)r0 * 2048 + c0, &lV[cur][db0]);
      gload_lds16(vg + (size_t)r1 * 2048 + c1, &lV[cur][db1]);
    }
    __syncthreads();

    for (int kt = 0; kt <= qt; ++kt) {
      if (kt < qt) {  // stage next tile into the other buffer (async)
        const int kb = (kt + 1) * 64;
        gload_lds16(kg + (size_t)(kb + r0) * 3072 + c0, &lK[cur ^ 1][db0]);
        gload_lds16(kg + (size_t)(kb + r1) * 3072 + c1, &lK[cur ^ 1][db1]);
        gload_lds16(vg + (size_t)r0 * 2048 + kb + c0, &lV[cur ^ 1][db0]);
        gload_lds16(vg + (size_t)r1 * 2048 + kb + c1, &lV[cur ^ 1][db1]);
      }
      const u16* const lKc = lK[cur];
      const u16* const lVc = lV[cur];
      // S^T[k][q]: k = f*16 + quad*4 + r, q = l16
      f32x4 s[4];
#pragma unroll
      for (int f = 0; f < 4; ++f) {
        const int rb = (f * 16 + l16) * 64;
        f32x4 a = z;
        a = mfma16(ld16(&lKc[rb + sl0]), aq0, a);
        a = mfma16(ld16(&lKc[rb + sl1]), aq1, a);
        s[f] = a * 0.180336879f;  // (1/8) * log2(e) -> base-2 softmax
      }
      // V^T fragments (A operand: rows d=f*16+l16, k-cols quad*8+e)
      bf16x8 vf0[4], vf1[4];
#pragma unroll
      for (int f = 0; f < 4; ++f) {
        const int rb = (f * 16 + l16) * 64;
        vf0[f] = ld16(&lVc[rb + sl0]);
        vf1[f] = ld16(&lVc[rb + sl1]);
      }
      if (kt == qt) {  // diagonal tile: mask k_local > q_local
#pragma unroll
        for (int f = 0; f < 4; ++f)
#pragma unroll
          for (int r = 0; r < 4; ++r)
            if (f * 16 + quad * 4 + r > wid * 16 + l16) s[f][r] = -1e30f;
      }
      // defer-max: rescale only when a lane's local max beats m_r + 8
      const f32x4 m4 = vmax4(vmax4(s[0], s[1]), vmax4(s[2], s[3]));
      const float pmax = fmaxf(fmaxf(m4[0], m4[1]), fmaxf(m4[2], m4[3]));
      if (__any(pmax > m_r + 8.f)) {  // wave-uniform branch
        float mm = fmaxf(pmax, __shfl_xor(pmax, 16));
        mm = fmaxf(mm, __shfl_xor(mm, 32));
        const float mn = fmaxf(m_r, mm);
        const float al = exp2f(m_r - mn);
        l_r *= al;
#pragma unroll
        for (int f = 0; f < 4; ++f)
#pragma unroll
          for (int r = 0; r < 4; ++r) o[f][r] *= al;
        m_r = mn;
      }
      // p = 2^(s - m), bounded by 2^8
#pragma unroll
      for (int f = 0; f < 4; ++f)
#pragma unroll
        for (int r = 0; r < 4; ++r) s[f][r] = exp2f(s[f][r] - m_r);
      const f32x4 s4 = (s[0] + s[1]) + (s[2] + s[3]);
      float sv = (s4[0] + s4[1]) + (s4[2] + s4[3]);
      sv += __shfl_xor(sv, 16);
      sv += __shfl_xor(sv, 32);
      l_r += sv;
      // pack P pairs and exchange -> PV B-fragments (in registers)
      u32 u00 = cvtpk(s[0][0], s[0][1]), u01 = cvtpk(s[0][2], s[0][3]);
      u32 u10 = cvtpk(s[1][0], s[1][1]), u11 = cvtpk(s[1][2], s[1][3]);
      u32 u20 = cvtpk(s[2][0], s[2][1]), u21 = cvtpk(s[2][2], s[2][3]);
      u32 u30 = cvtpk(s[3][0], s[3][1]), u31 = cvtpk(s[3][2], s[3][3]);
      u32x4 P0, P1;
      {
        u32 A0 = u00, B0 = u10, A1 = u01, B1 = u11;
        plane32_swap(A0, B0);
        plane32_swap(A1, B1);
        u32 Y0 = qodd ? A0 : B0;
        u32 Y1 = qodd ? A1 : B1;
        Y0 = (u32)__shfl_xor((int)Y0, 16);
        Y1 = (u32)__shfl_xor((int)Y1, 16);
        P0[0] = qodd ? Y0 : A0;
        P0[1] = qodd ? Y1 : A1;
        P0[2] = qodd ? B0 : Y0;
        P0[3] = qodd ? B1 : Y1;
      }
      {
        u32 A0 = u20, B0 = u30, A1 = u21, B1 = u31;
        plane32_swap(A0, B0);
        plane32_swap(A1, B1);
        u32 Y0 = qodd ? A0 : B0;
        u32 Y1 = qodd ? A1 : B1;
        Y0 = (u32)__shfl_xor((int)Y0, 16);
        Y1 = (u32)__shfl_xor((int)Y1, 16);
        P1[0] = qodd ? Y0 : A0;
        P1[1] = qodd ? Y1 : A1;
        P1[2] = qodd ? B0 : Y0;
        P1[3] = qodd ? B1 : Y1;
      }
      const bf16x8 pb0 = __builtin_bit_cast(bf16x8, P0);
      const bf16x8 pb1 = __builtin_bit_cast(bf16x8, P1);
      // O^T[d][q] += V^T * P^T
#pragma unroll
      for (int f = 0; f < 4; ++f) {
        o[f] = mfma16(vf0[f], pb0, o[f]);
        o[f] = mfma16(vf1[f], pb1, o[f]);
      }
      __syncthreads();  // drains vmcnt (next tile staged) + lgkm; WAR for buf
      cur ^= 1;
    }
    // epilogue: o[f][r] = O^T[d=f*16+quad*4+r][q=l16]; direct 8B stores
    const float inv = 1.0f / l_r;
#pragma unroll
    for (int f = 0; f < 4; ++f) {
      uint2a wv;
      wv.x = cvtpk(o[f][0] * inv, o[f][1] * inv);
      wv.y = cvtpk(o[f][2] * inv, o[f][3] * inv);
      *(uint2a*)&aout[(size_t)(b * SEQ + q0 + l16) * 1024 + h * 64 + f * 16 +
                      quad * 4] = wv;
    }
  }
}

extern "C" void kernel_launch(void* const* d_in, const int* in_sizes, int n_in,
                              void* d_out, int out_size, void* d_ws, size_t ws_size,
                              hipStream_t stream) {
  const void* x     = d_in[0];
  const void* w_qkv = d_in[1];
  const void* b_qkv = d_in[2];
  const void* w_out = d_in[3];
  const void* b_out = d_in[4];
  float* out = (float*)d_out;  // reference output dtype is fp32

  // common prefix
  float* bqf   = (float*)d_ws;                      // [3072] fp32
  float* bof   = bqf + 3072;                        // [1024] fp32
  int*   flag  = (int*)(bof + 1024);                // [4]
  u16*   wqkvT = (u16*)(flag + 4);                  // [3072,1024]
  u16*   woutT = wqkvT + (size_t)3072 * 1024;       // [1024,1024]
  u16*   xb    = woutT + (size_t)1024 * 1024;       // [M,1024]

  detect_dtype<<<dim3(1), dim3(64), 0, stream>>>((const u16*)x, flag);
  cvt_bias<<<dim3(12), dim3(256), 0, stream>>>(b_qkv, bqf, 3072, flag);
  cvt_bias<<<dim3(4), dim3(256), 0, stream>>>(b_out, bof, 1024, flag);
  transpose_w<<<dim3(48, 16), dim3(256), 0, stream>>>(w_qkv, wqkvT, 1024, 3072, flag);
  transpose_w<<<dim3(16, 16), dim3(256), 0, stream>>>(w_out, woutT, 1024, 1024, flag);

  // full-batch path needs 92,291,088 B of ws; fall back to per-batch otherwise.
  const size_t FULL_WS = 92291088;  // constant across calls -> graph-safe branch
  if (ws_size >= FULL_WS) {
    u16* qkv = xb  + (size_t)8192 * 1024;           // [8192,3072]
    u16* vt  = qkv + (size_t)8192 * 3072;           // [64,64,2048]
    cvt_x<<<dim3(8192), dim3(256), 0, stream>>>(x, xb, flag, 0);
    gemm_bt<true ><<<dim3(24, 64), dim3(256), 0, stream>>>(xb, wqkvT, bqf, qkv,
                                                           8192, 3072, 1024);
    transpose_v<<<dim3(16, 32, 4), dim3(256), 0, stream>>>(qkv, vt);
    attn_fwd<<<dim3(16, 16, 4), dim3(256), 0, stream>>>(qkv, vt, xb);
    gemm_bt<false><<<dim3(8, 64), dim3(256), 0, stream>>>(xb, woutT, bof, out,
                                                          8192, 1024, 1024);
  } else {
    u16* qkvb = xb   + (size_t)2048 * 1024;         // [2048,3072]
    u16* vtb  = qkvb + (size_t)2048 * 3072;         // [16,64,2048]
    for (int b = 0; b < 4; ++b) {
      const size_t eoff4 = (size_t)b * 2048 * 1024 / 4;
      cvt_x<<<dim3(2048), dim3(256), 0, stream>>>(x, xb, flag, eoff4);
      gemm_bt<true ><<<dim3(24, 16), dim3(256), 0, stream>>>(xb, wqkvT, bqf, qkvb,
                                                             2048, 3072, 1024);
      transpose_v<<<dim3(16, 32, 1), dim3(256), 0, stream>>>(qkvb, vtb);
      attn_fwd<<<dim3(16, 16, 1), dim3(256), 0, stream>>>(qkvb, vtb, xb);
      gemm_bt<false><<<dim3(8, 16), dim3(256), 0, stream>>>(
          xb, woutT, bof, out + (size_t)b * 2048 * 1024, 2048, 1024, 1024);
    }
  }
}

// Round 3
// 307.289 us; speedup vs baseline: 1.7736x; 1.0852x over previous
//
#include <hip/hip_runtime.h>

typedef unsigned short u16;
typedef unsigned int u32;
using f32x4 = __attribute__((ext_vector_type(4))) float;
using u32x4 = __attribute__((ext_vector_type(4))) u32;
typedef u32x4 __attribute__((may_alias)) u32x4a;  // TBAA-safe 16B vector
typedef uint2 __attribute__((may_alias)) uint2a;  // TBAA-safe 8B vector
using bf16x8 = __attribute__((ext_vector_type(8))) __bf16;

#define SEQ 2048  // per batch

// fp32 -> bf16 round-to-nearest-even
__device__ __forceinline__ u16 f2bf(float f) {
  union { float f; u32 u; } c; c.f = f;
  return (u16)((c.u + 0x7fffu + ((c.u >> 16) & 1u)) >> 16);
}
__device__ __forceinline__ float bf2f(u16 h) {
  union { u32 u; float f; } c; c.u = ((u32)h) << 16;
  return c.f;
}
__device__ __forceinline__ bf16x8 ld16(const u16* p) {
  return __builtin_bit_cast(bf16x8, *(const u32x4a*)p);
}
__device__ __forceinline__ f32x4 mfma16(bf16x8 a, bf16x8 b, f32x4 c) {
  return __builtin_amdgcn_mfma_f32_16x16x32_bf16(a, b, c, 0, 0, 0);
}
// async global->LDS, 16B/lane; LDS dest = wave-uniform base + lane*16
__device__ __forceinline__ void gload_lds16(const u16* g, u16* l) {
  __builtin_amdgcn_global_load_lds(
      (const __attribute__((address_space(1))) void*)g,
      (__attribute__((address_space(3))) void*)l, 16, 0, 0);
}
// pack 2 fp32 -> 1 u32 of 2 bf16 (RNE); no builtin on gfx950
__device__ __forceinline__ u32 cvtpk(float lo, float hi) {
  u32 r;
  asm("v_cvt_pk_bf16_f32 %0, %1, %2" : "=v"(r) : "v"(lo), "v"(hi));
  return r;
}
// new_a = [a.lanes0-31 | b.lanes0-31], new_b = [a.lanes32-63 | b.lanes32-63]
__device__ __forceinline__ void plane32_swap(u32& a, u32& b) {
  asm("v_permlane32_swap_b32 %0, %1" : "+v"(a), "+v"(b));
}
__device__ __forceinline__ f32x4 vmax4(f32x4 a, f32x4 b) {
  f32x4 r;
  r[0] = fmaxf(a[0], b[0]); r[1] = fmaxf(a[1], b[1]);
  r[2] = fmaxf(a[2], b[2]); r[3] = fmaxf(a[3], b[3]);
  return r;
}

// ---------------- input dtype detection ----------------
__global__ void detect_dtype(const u16* __restrict__ x, int* __restrict__ flag) {
  if (threadIdx.x == 0) {
    int cnt = 0;
    for (int i = 0; i < 32; ++i) {
      const int e = (x[2 * i] >> 7) & 0xFF;
      cnt += (e >= 100 && e <= 140) ? 1 : 0;
    }
    *flag = (cnt >= 20) ? 1 : 0;  // 1 = inputs are bf16
  }
}

// ---------------- prep kernels ----------------

__global__ __launch_bounds__(256)
void cvt_x(const void* __restrict__ in, u16* __restrict__ out,
           const int* __restrict__ flag, size_t eoff4) {
  const size_t i = (size_t)blockIdx.x * 256 + threadIdx.x;
  if (*flag) {
    ((uint2*)out)[i] = ((const uint2*)in)[eoff4 + i];
  } else {
    const float4 v = ((const float4*)in)[eoff4 + i];
    uint2 ov;
    ov.x = (u32)f2bf(v.x) | ((u32)f2bf(v.y) << 16);
    ov.y = (u32)f2bf(v.z) | ((u32)f2bf(v.w) << 16);
    ((uint2*)out)[i] = ov;
  }
}

__global__ __launch_bounds__(256)
void cvt_bias(const void* __restrict__ in, float* __restrict__ out, int n,
              const int* __restrict__ flag) {
  const int i = blockIdx.x * 256 + threadIdx.x;
  if (i >= n) return;
  out[i] = (*flag) ? bf2f(((const u16*)in)[i]) : ((const float*)in)[i];
}

// in [K,N] (fp32 or bf16) -> out bf16 [N,K]. 64x64 tiles via LDS.
__global__ __launch_bounds__(256)
void transpose_w(const void* __restrict__ in, u16* __restrict__ out, int K, int N,
                 const int* __restrict__ flag) {
  __shared__ float t[64][65];
  const int tid = threadIdx.x;
  const int r = tid >> 4, c4 = tid & 15;
  const int n0 = blockIdx.x << 6, k0 = blockIdx.y << 6;
  const int fl = *flag;
#pragma unroll
  for (int i = 0; i < 4; ++i) {
    const int kk = r + i * 16;
    const size_t base = (size_t)(k0 + kk) * N + n0 + c4 * 4;
    if (fl) {
      const uint2 raw = *(const uint2*)((const u16*)in + base);
      t[kk][c4 * 4 + 0] = bf2f((u16)(raw.x & 0xFFFF));
      t[kk][c4 * 4 + 1] = bf2f((u16)(raw.x >> 16));
      t[kk][c4 * 4 + 2] = bf2f((u16)(raw.y & 0xFFFF));
      t[kk][c4 * 4 + 3] = bf2f((u16)(raw.y >> 16));
    } else {
      const float4 v = *(const float4*)((const float*)in + base);
      t[kk][c4 * 4 + 0] = v.x; t[kk][c4 * 4 + 1] = v.y;
      t[kk][c4 * 4 + 2] = v.z; t[kk][c4 * 4 + 3] = v.w;
    }
  }
  __syncthreads();
#pragma unroll
  for (int i = 0; i < 4; ++i) {
    const int nn = r + i * 16;
    uint2 ov;
    ov.x = (u32)f2bf(t[c4 * 4 + 0][nn]) | ((u32)f2bf(t[c4 * 4 + 1][nn]) << 16);
    ov.y = (u32)f2bf(t[c4 * 4 + 2][nn]) | ((u32)f2bf(t[c4 * 4 + 3][nn]) << 16);
    *(uint2*)&out[(size_t)(n0 + nn) * K + k0 + c4 * 4] = ov;
  }
}

// qkv bf16 [nb*2048, 3072] (V cols 2048..3071) -> vt [nb*16][d=64][s=2048]
__global__ __launch_bounds__(256)
void transpose_v(const u16* __restrict__ qkv, u16* __restrict__ vt) {
  __shared__ __align__(16) u16 t[64][72];
  const int h = blockIdx.x, s0 = blockIdx.y << 6, b = blockIdx.z;
  const int tid = threadIdx.x;
  const int r = tid >> 2, g = tid & 3;
  const u16* src = &qkv[(size_t)(b * SEQ + s0 + r) * 3072 + 2048 + h * 64 + g * 16];
  *(u32x4a*)&t[r][g * 16]     = *(const u32x4a*)src;
  *(u32x4a*)&t[r][g * 16 + 8] = *(const u32x4a*)(src + 8);
  __syncthreads();
  union { u16 s[16]; u32x4 v[2]; } u;
#pragma unroll
  for (int e = 0; e < 16; ++e) u.s[e] = t[g * 16 + e][r];
  u16* dst = &vt[(size_t)((b * 16 + h) * 64 + r) * 2048 + s0 + g * 16];
  *(u32x4a*)dst = u.v[0];
  *(u32x4a*)(dst + 8) = u.v[1];
}

// ---------------- GEMM: C[M,N] = A[M,K]*BT[N,K]^T + bias ----------------
// 256x128 tile, BK=32, 512 threads (8 waves, 4M x 2N, 64x64 per wave).
// Ring of 4 LDS buffers (96 KiB), prefetch distance 3, counted vmcnt(6)
// (never 0 in main loop -- in-order vmcnt retirement guarantees tile kt is
// resident while kt+1..kt+3 stay in flight). Raw s_barrier (one per iter) +
// inline-asm waits (T3/T4); setprio around MFMA cluster (T5).
// LDS swizzle (T2, rule #21 both-sides): granule (16B) slot s of row r maps
// to source col granule s ^ ((r&3)^((r>>2)&3)); verified perfect 2-way bank
// spread (free) for the stride-64B fragment reads. Stage writes stay linear
// (global_load_lds HW rule); source address is pre-swizzled; ds_read applies
// the same XOR.
template <bool BF16_OUT>
__global__ __launch_bounds__(512, 2)
void gemm_bt(const u16* __restrict__ A, const u16* __restrict__ BT,
             const float* __restrict__ bias, void* __restrict__ Cv,
             int M, int N, int K) {
  constexpr int BK = 32;
  // per buffer: A 256x32 (16 KB) + B 128x32 (8 KB) u16
  __shared__ __align__(16) u16 ring[4][12288];
  const int tid = threadIdx.x;
  const int wid = tid >> 6, lane = tid & 63;
  const int quad = lane >> 4, l16 = lane & 15;

  // grid flatten + bijective XCD swizzle (all launch shapes have nwg%8==0)
  const int nbx = gridDim.x, nwg = nbx * gridDim.y;
  int bid = blockIdx.y * nbx + blockIdx.x;
  if ((nwg & 7) == 0) bid = (bid & 7) * (nwg >> 3) + (bid >> 3);
  const int tile_n = (bid % nbx) << 7;  // BN=128
  const int tile_m = (bid / nbx) << 8;  // BM=256

  const int wmR = (wid >> 1) << 6;  // 0,64,128,192
  const int wnR = (wid & 1) << 6;   // 0,64

  // stage geometry: granule G -> row=G>>2, slot=G&3; source col granule =
  // slot ^ sw(row), sw(r) = (r&3)^((r>>2)&3). A: G in [0,1024) (2 rounds),
  // B: G in [0,512) (1 round, shares G0 geometry).
  const int G0 = wid * 64 + lane;
  const int rA0 = G0 >> 2;
  const int sA0 = (((G0 & 3) ^ ((rA0 & 3) ^ ((rA0 >> 2) & 3)))) * 8;
  const int G1 = G0 + 512;
  const int rA1 = G1 >> 2;
  const int sA1 = (((G1 & 3) ^ ((rA1 & 3) ^ ((rA1 >> 2) & 3)))) * 8;
  const u16* const pA0 = A + (size_t)(tile_m + rA0) * K + sA0;
  const u16* const pA1 = A + (size_t)(tile_m + rA1) * K + sA1;
  const u16* const pB0 = BT + (size_t)(tile_n + rA0) * K + sA0;
  const int dst0 = wid * 512;          // u16 offset in buffer (wave-uniform)
  const int dst1 = 4096 + wid * 512;
  const int dstB = 8192 + wid * 512;

  // fragment-read swizzle: rows are base16+l16 -> sw(row) depends on l16 only
  const int swl = (l16 & 3) ^ ((l16 >> 2) & 3);
  const int cA = (quad ^ swl) * 8;

  const int nk = K >> 5;
  f32x4 acc[4][4] = {};

  auto STAGE = [&](int kt) {
    u16* bp = ring[kt & 3];
    const size_t ko = (size_t)kt * BK;
    gload_lds16(pA0 + ko, bp + dst0);
    gload_lds16(pA1 + ko, bp + dst1);
    gload_lds16(pB0 + ko, bp + dstB);
  };

  STAGE(0);
  if (nk > 1) STAGE(1);
  if (nk > 2) STAGE(2);

  for (int kt = 0; kt < nk; ++kt) {
    // my stage(kt) complete (oldest 3 of <=9 outstanding retire first)
    asm volatile("s_waitcnt vmcnt(6)" ::: "memory");
    __builtin_amdgcn_sched_barrier(0);
    __builtin_amdgcn_s_barrier();  // all waves' stage(kt) complete; and all
                                   // reads of buf[(kt-1)&3] finished (lgkm(0)
                                   // before prev MFMAs) -> safe to overwrite
    __builtin_amdgcn_sched_barrier(0);
    if (kt + 3 < nk) STAGE(kt + 3);  // writes buf[(kt-1)&3]
    const u16* bp = ring[kt & 3];
    bf16x8 af[4], bfr[4];
#pragma unroll
    for (int i = 0; i < 4; ++i)
      af[i] = ld16(&bp[(wmR + i * 16 + l16) * BK + cA]);
#pragma unroll
    for (int j = 0; j < 4; ++j)
      bfr[j] = ld16(&bp[8192 + (wnR + j * 16 + l16) * BK + cA]);
    asm volatile("s_waitcnt lgkmcnt(0)" ::: "memory");
    __builtin_amdgcn_sched_barrier(0);  // rule #18: keep MFMA below the wait
    __builtin_amdgcn_s_setprio(1);
#pragma unroll
    for (int i = 0; i < 4; ++i)
#pragma unroll
      for (int j = 0; j < 4; ++j) acc[i][j] = mfma16(af[i], bfr[j], acc[i][j]);
    __builtin_amdgcn_s_setprio(0);
  }

#pragma unroll
  for (int j = 0; j < 4; ++j) {
    const int cg = tile_n + wnR + j * 16 + l16;
    const float bv = bias[cg];
#pragma unroll
    for (int i = 0; i < 4; ++i) {
      const int rg = tile_m + wmR + i * 16 + quad * 4;
#pragma unroll
      for (int r = 0; r < 4; ++r) {
        const float v = acc[i][j][r] + bv;
        if constexpr (BF16_OUT)
          ((u16*)Cv)[(size_t)(rg + r) * N + cg] = f2bf(v);
        else
          ((float*)Cv)[(size_t)(rg + r) * N + cg] = v;
      }
    }
  }
}

// ---------------- causal flash attention ----------------
// grid (16 h, 16 pair-slots, nb). Block y does q-tiles {31-y, y}: uniform 33
// k-iterations. Swapped QK (S^T), in-register softmax/P-exchange. K/V tiles
// staged once per block into double-buffered LDS via global_load_lds; stage
// of kt+1 issued at top of iter kt, drained by end-of-iter __syncthreads.
// LDS rows pre-swizzled at the global source + same XOR on ds_read.
// T13 defer-max (base-2, THR=8); exp2 with log2e folded into QK scale.
__global__ __launch_bounds__(256, 4)
void attn_fwd(const u16* __restrict__ qkv, const u16* __restrict__ vt,
              u16* __restrict__ aout) {
  const int h = blockIdx.x, b = blockIdx.z;
  const int tid = threadIdx.x, wid = tid >> 6, lane = tid & 63;
  const int quad = lane >> 4, l16 = lane & 15;
  const int qodd = quad & 1;
  __shared__ __align__(16) u16 lK[2][4096];  // [buf][64 rows x 64 cols]
  __shared__ __align__(16) u16 lV[2][4096];  // [buf][64 d x 64 k]

  const int G0 = wid * 64 + lane, G1 = G0 + 256;
  const int r0 = G0 >> 3, c0 = ((G0 & 7) ^ (r0 & 7)) * 8;
  const int r1 = G1 >> 3, c1 = ((G1 & 7) ^ (r1 & 7)) * 8;
  const int db0 = wid * 512, db1 = 2048 + wid * 512;

  const u16* const kg = qkv + (size_t)(b * SEQ) * 3072 + 1024 + h * 64;
  const u16* const vg = vt + (size_t)((b * 16 + h) * 64) * 2048;

  const int sl0 = (quad ^ (l16 & 7)) * 8;
  const int sl1 = sl0 ^ 32;

  const f32x4 z = {0.f, 0.f, 0.f, 0.f};
  int cur = 0;

#pragma unroll 1
  for (int pass = 0; pass < 2; ++pass) {
    const int qt = pass ? (int)blockIdx.y : 31 - (int)blockIdx.y;
    const int q0 = qt * 64 + wid * 16;
    const size_t qi = (size_t)(b * SEQ + q0 + l16) * 3072 + h * 64 + quad * 8;
    const bf16x8 aq0 = ld16(&qkv[qi]);
    const bf16x8 aq1 = ld16(&qkv[qi + 32]);
    f32x4 o[4] = {z, z, z, z};
    float m_r = -1e30f, l_r = 0.f;

    {
      gload_lds16(kg + (size_t)r0 * 3072 + c0, &lK[cur][db0]);
      gload_lds16(kg + (size_t)r1 * 3072 + c1, &lK[cur][db1]);
      gload_lds16(vg + (size_t)r0 * 2048 + c0, &lV[cur][db0]);
      gload_lds16(vg + (size_t)r1 * 2048 + c1, &lV[cur][db1]);
    }
    __syncthreads();

    for (int kt = 0; kt <= qt; ++kt) {
      if (kt < qt) {
        const int kb = (kt + 1) * 64;
        gload_lds16(kg + (size_t)(kb + r0) * 3072 + c0, &lK[cur ^ 1][db0]);
        gload_lds16(kg + (size_t)(kb + r1) * 3072 + c1, &lK[cur ^ 1][db1]);
        gload_lds16(vg + (size_t)r0 * 2048 + kb + c0, &lV[cur ^ 1][db0]);
        gload_lds16(vg + (size_t)r1 * 2048 + kb + c1, &lV[cur ^ 1][db1]);
      }
      const u16* const lKc = lK[cur];
      const u16* const lVc = lV[cur];
      f32x4 s[4];
#pragma unroll
      for (int f = 0; f < 4; ++f) {
        const int rb = (f * 16 + l16) * 64;
        f32x4 a = z;
        a = mfma16(ld16(&lKc[rb + sl0]), aq0, a);
        a = mfma16(ld16(&lKc[rb + sl1]), aq1, a);
        s[f] = a * 0.180336879f;  // (1/8) * log2(e) -> base-2 softmax
      }
      bf16x8 vf0[4], vf1[4];
#pragma unroll
      for (int f = 0; f < 4; ++f) {
        const int rb = (f * 16 + l16) * 64;
        vf0[f] = ld16(&lVc[rb + sl0]);
        vf1[f] = ld16(&lVc[rb + sl1]);
      }
      if (kt == qt) {
#pragma unroll
        for (int f = 0; f < 4; ++f)
#pragma unroll
          for (int r = 0; r < 4; ++r)
            if (f * 16 + quad * 4 + r > wid * 16 + l16) s[f][r] = -1e30f;
      }
      const f32x4 m4 = vmax4(vmax4(s[0], s[1]), vmax4(s[2], s[3]));
      const float pmax = fmaxf(fmaxf(m4[0], m4[1]), fmaxf(m4[2], m4[3]));
      if (__any(pmax > m_r + 8.f)) {
        float mm = fmaxf(pmax, __shfl_xor(pmax, 16));
        mm = fmaxf(mm, __shfl_xor(mm, 32));
        const float mn = fmaxf(m_r, mm);
        const float al = exp2f(m_r - mn);
        l_r *= al;
#pragma unroll
        for (int f = 0; f < 4; ++f)
#pragma unroll
          for (int r = 0; r < 4; ++r) o[f][r] *= al;
        m_r = mn;
      }
#pragma unroll
      for (int f = 0; f < 4; ++f)
#pragma unroll
        for (int r = 0; r < 4; ++r) s[f][r] = exp2f(s[f][r] - m_r);
      const f32x4 s4 = (s[0] + s[1]) + (s[2] + s[3]);
      float sv = (s4[0] + s4[1]) + (s4[2] + s4[3]);
      sv += __shfl_xor(sv, 16);
      sv += __shfl_xor(sv, 32);
      l_r += sv;
      u32 u00 = cvtpk(s[0][0], s[0][1]), u01 = cvtpk(s[0][2], s[0][3]);
      u32 u10 = cvtpk(s[1][0], s[1][1]), u11 = cvtpk(s[1][2], s[1][3]);
      u32 u20 = cvtpk(s[2][0], s[2][1]), u21 = cvtpk(s[2][2], s[2][3]);
      u32 u30 = cvtpk(s[3][0], s[3][1]), u31 = cvtpk(s[3][2], s[3][3]);
      u32x4 P0, P1;
      {
        u32 A0 = u00, B0 = u10, A1 = u01, B1 = u11;
        plane32_swap(A0, B0);
        plane32_swap(A1, B1);
        u32 Y0 = qodd ? A0 : B0;
        u32 Y1 = qodd ? A1 : B1;
        Y0 = (u32)__shfl_xor((int)Y0, 16);
        Y1 = (u32)__shfl_xor((int)Y1, 16);
        P0[0] = qodd ? Y0 : A0;
        P0[1] = qodd ? Y1 : A1;
        P0[2] = qodd ? B0 : Y0;
        P0[3] = qodd ? B1 : Y1;
      }
      {
        u32 A0 = u20, B0 = u30, A1 = u21, B1 = u31;
        plane32_swap(A0, B0);
        plane32_swap(A1, B1);
        u32 Y0 = qodd ? A0 : B0;
        u32 Y1 = qodd ? A1 : B1;
        Y0 = (u32)__shfl_xor((int)Y0, 16);
        Y1 = (u32)__shfl_xor((int)Y1, 16);
        P1[0] = qodd ? Y0 : A0;
        P1[1] = qodd ? Y1 : A1;
        P1[2] = qodd ? B0 : Y0;
        P1[3] = qodd ? B1 : Y1;
      }
      const bf16x8 pb0 = __builtin_bit_cast(bf16x8, P0);
      const bf16x8 pb1 = __builtin_bit_cast(bf16x8, P1);
#pragma unroll
      for (int f = 0; f < 4; ++f) {
        o[f] = mfma16(vf0[f], pb0, o[f]);
        o[f] = mfma16(vf1[f], pb1, o[f]);
      }
      __syncthreads();
      cur ^= 1;
    }
    const float inv = 1.0f / l_r;
#pragma unroll
    for (int f = 0; f < 4; ++f) {
      uint2a wv;
      wv.x = cvtpk(o[f][0] * inv, o[f][1] * inv);
      wv.y = cvtpk(o[f][2] * inv, o[f][3] * inv);
      *(uint2a*)&aout[(size_t)(b * SEQ + q0 + l16) * 1024 + h * 64 + f * 16 +
                      quad * 4] = wv;
    }
  }
}

extern "C" void kernel_launch(void* const* d_in, const int* in_sizes, int n_in,
                              void* d_out, int out_size, void* d_ws, size_t ws_size,
                              hipStream_t stream) {
  const void* x     = d_in[0];
  const void* w_qkv = d_in[1];
  const void* b_qkv = d_in[2];
  const void* w_out = d_in[3];
  const void* b_out = d_in[4];
  float* out = (float*)d_out;  // reference output dtype is fp32

  // common prefix
  float* bqf   = (float*)d_ws;                      // [3072] fp32
  float* bof   = bqf + 3072;                        // [1024] fp32
  int*   flag  = (int*)(bof + 1024);                // [4]
  u16*   wqkvT = (u16*)(flag + 4);                  // [3072,1024]
  u16*   woutT = wqkvT + (size_t)3072 * 1024;       // [1024,1024]
  u16*   xb    = woutT + (size_t)1024 * 1024;       // [M,1024]

  detect_dtype<<<dim3(1), dim3(64), 0, stream>>>((const u16*)x, flag);
  cvt_bias<<<dim3(12), dim3(256), 0, stream>>>(b_qkv, bqf, 3072, flag);
  cvt_bias<<<dim3(4), dim3(256), 0, stream>>>(b_out, bof, 1024, flag);
  transpose_w<<<dim3(48, 16), dim3(256), 0, stream>>>(w_qkv, wqkvT, 1024, 3072, flag);
  transpose_w<<<dim3(16, 16), dim3(256), 0, stream>>>(w_out, woutT, 1024, 1024, flag);

  // full-batch path needs 92,291,088 B of ws; fall back to per-batch otherwise.
  const size_t FULL_WS = 92291088;  // constant across calls -> graph-safe branch
  if (ws_size >= FULL_WS) {
    u16* qkv = xb  + (size_t)8192 * 1024;           // [8192,3072]
    u16* vt  = qkv + (size_t)8192 * 3072;           // [64,64,2048]
    cvt_x<<<dim3(8192), dim3(256), 0, stream>>>(x, xb, flag, 0);
    gemm_bt<true ><<<dim3(24, 32), dim3(512), 0, stream>>>(xb, wqkvT, bqf, qkv,
                                                           8192, 3072, 1024);
    transpose_v<<<dim3(16, 32, 4), dim3(256), 0, stream>>>(qkv, vt);
    attn_fwd<<<dim3(16, 16, 4), dim3(256), 0, stream>>>(qkv, vt, xb);
    gemm_bt<false><<<dim3(8, 32), dim3(512), 0, stream>>>(xb, woutT, bof, out,
                                                          8192, 1024, 1024);
  } else {
    u16* qkvb = xb   + (size_t)2048 * 1024;         // [2048,3072]
    u16* vtb  = qkvb + (size_t)2048 * 3072;         // [16,64,2048]
    for (int b = 0; b < 4; ++b) {
      const size_t eoff4 = (size_t)b * 2048 * 1024 / 4;
      cvt_x<<<dim3(2048), dim3(256), 0, stream>>>(x, xb, flag, eoff4);
      gemm_bt<true ><<<dim3(24, 8), dim3(512), 0, stream>>>(xb, wqkvT, bqf, qkvb,
                                                            2048, 3072, 1024);
      transpose_v<<<dim3(16, 32, 1), dim3(256), 0, stream>>>(qkvb, vtb);
      attn_fwd<<<dim3(16, 16, 1), dim3(256), 0, stream>>>(qkvb, vtb, xb);
      gemm_bt<false><<<dim3(8, 8), dim3(512), 0, stream>>>(
          xb, woutT, bof, out + (size_t)b * 2048 * 1024, 2048, 1024, 1024);
    }
  }
}

// Round 4
// 299.117 us; speedup vs baseline: 1.8221x; 1.0273x over previous
//
#include <hip/hip_runtime.h>

typedef unsigned short u16;
typedef unsigned int u32;
using f32x4 = __attribute__((ext_vector_type(4))) float;
using f32x16 = __attribute__((ext_vector_type(16))) float;
using u32x4 = __attribute__((ext_vector_type(4))) u32;
typedef u32x4 __attribute__((may_alias)) u32x4a;  // TBAA-safe 16B vector
typedef uint2 __attribute__((may_alias)) uint2a;  // TBAA-safe 8B vector
using bf16x8 = __attribute__((ext_vector_type(8))) __bf16;

#define SEQ 2048  // per batch

// fp32 -> bf16 round-to-nearest-even
__device__ __forceinline__ u16 f2bf(float f) {
  union { float f; u32 u; } c; c.f = f;
  return (u16)((c.u + 0x7fffu + ((c.u >> 16) & 1u)) >> 16);
}
__device__ __forceinline__ float bf2f(u16 h) {
  union { u32 u; float f; } c; c.u = ((u32)h) << 16;
  return c.f;
}
__device__ __forceinline__ bf16x8 ld16(const u16* p) {
  return __builtin_bit_cast(bf16x8, *(const u32x4a*)p);
}
__device__ __forceinline__ f32x4 mfma16(bf16x8 a, bf16x8 b, f32x4 c) {
  return __builtin_amdgcn_mfma_f32_16x16x32_bf16(a, b, c, 0, 0, 0);
}
__device__ __forceinline__ f32x16 mfma32(bf16x8 a, bf16x8 b, f32x16 c) {
  return __builtin_amdgcn_mfma_f32_32x32x16_bf16(a, b, c, 0, 0, 0);
}
// async global->LDS, 16B/lane; LDS dest = wave-uniform base + lane*16
__device__ __forceinline__ void gload_lds16(const u16* g, u16* l) {
  __builtin_amdgcn_global_load_lds(
      (const __attribute__((address_space(1))) void*)g,
      (__attribute__((address_space(3))) void*)l, 16, 0, 0);
}
// pack 2 fp32 -> 1 u32 of 2 bf16 (RNE); no builtin on gfx950
__device__ __forceinline__ u32 cvtpk(float lo, float hi) {
  u32 r;
  asm("v_cvt_pk_bf16_f32 %0, %1, %2" : "=v"(r) : "v"(lo), "v"(hi));
  return r;
}
// new_a = [a.lanes0-31 | b.lanes0-31], new_b = [a.lanes32-63 | b.lanes32-63]
__device__ __forceinline__ void plane32_swap(u32& a, u32& b) {
  asm("v_permlane32_swap_b32 %0, %1" : "+v"(a), "+v"(b));
}

// ---------------- input dtype detection ----------------
__global__ void detect_dtype(const u16* __restrict__ x, int* __restrict__ flag) {
  if (threadIdx.x == 0) {
    int cnt = 0;
    for (int i = 0; i < 32; ++i) {
      const int e = (x[2 * i] >> 7) & 0xFF;
      cnt += (e >= 100 && e <= 140) ? 1 : 0;
    }
    *flag = (cnt >= 20) ? 1 : 0;  // 1 = inputs are bf16
  }
}

// ---------------- prep kernels ----------------

__global__ __launch_bounds__(256)
void cvt_x(const void* __restrict__ in, u16* __restrict__ out,
           const int* __restrict__ flag, size_t eoff4) {
  const size_t i = (size_t)blockIdx.x * 256 + threadIdx.x;
  if (*flag) {
    ((uint2*)out)[i] = ((const uint2*)in)[eoff4 + i];
  } else {
    const float4 v = ((const float4*)in)[eoff4 + i];
    uint2 ov;
    ov.x = (u32)f2bf(v.x) | ((u32)f2bf(v.y) << 16);
    ov.y = (u32)f2bf(v.z) | ((u32)f2bf(v.w) << 16);
    ((uint2*)out)[i] = ov;
  }
}

__global__ __launch_bounds__(256)
void cvt_bias(const void* __restrict__ in, float* __restrict__ out, int n,
              const int* __restrict__ flag) {
  const int i = blockIdx.x * 256 + threadIdx.x;
  if (i >= n) return;
  out[i] = (*flag) ? bf2f(((const u16*)in)[i]) : ((const float*)in)[i];
}

// in [K,N] (fp32 or bf16) -> out bf16 [N,K]. 64x64 tiles via LDS.
__global__ __launch_bounds__(256)
void transpose_w(const void* __restrict__ in, u16* __restrict__ out, int K, int N,
                 const int* __restrict__ flag) {
  __shared__ float t[64][65];
  const int tid = threadIdx.x;
  const int r = tid >> 4, c4 = tid & 15;
  const int n0 = blockIdx.x << 6, k0 = blockIdx.y << 6;
  const int fl = *flag;
#pragma unroll
  for (int i = 0; i < 4; ++i) {
    const int kk = r + i * 16;
    const size_t base = (size_t)(k0 + kk) * N + n0 + c4 * 4;
    if (fl) {
      const uint2 raw = *(const uint2*)((const u16*)in + base);
      t[kk][c4 * 4 + 0] = bf2f((u16)(raw.x & 0xFFFF));
      t[kk][c4 * 4 + 1] = bf2f((u16)(raw.x >> 16));
      t[kk][c4 * 4 + 2] = bf2f((u16)(raw.y & 0xFFFF));
      t[kk][c4 * 4 + 3] = bf2f((u16)(raw.y >> 16));
    } else {
      const float4 v = *(const float4*)((const float*)in + base);
      t[kk][c4 * 4 + 0] = v.x; t[kk][c4 * 4 + 1] = v.y;
      t[kk][c4 * 4 + 2] = v.z; t[kk][c4 * 4 + 3] = v.w;
    }
  }
  __syncthreads();
#pragma unroll
  for (int i = 0; i < 4; ++i) {
    const int nn = r + i * 16;
    uint2 ov;
    ov.x = (u32)f2bf(t[c4 * 4 + 0][nn]) | ((u32)f2bf(t[c4 * 4 + 1][nn]) << 16);
    ov.y = (u32)f2bf(t[c4 * 4 + 2][nn]) | ((u32)f2bf(t[c4 * 4 + 3][nn]) << 16);
    *(uint2*)&out[(size_t)(n0 + nn) * K + k0 + c4 * 4] = ov;
  }
}

// qkv bf16 [nb*2048, 3072] (V cols 2048..3071) -> vt [nb*16][d=64][s=2048]
__global__ __launch_bounds__(256)
void transpose_v(const u16* __restrict__ qkv, u16* __restrict__ vt) {
  __shared__ __align__(16) u16 t[64][72];
  const int h = blockIdx.x, s0 = blockIdx.y << 6, b = blockIdx.z;
  const int tid = threadIdx.x;
  const int r = tid >> 2, g = tid & 3;
  const u16* src = &qkv[(size_t)(b * SEQ + s0 + r) * 3072 + 2048 + h * 64 + g * 16];
  *(u32x4a*)&t[r][g * 16]     = *(const u32x4a*)src;
  *(u32x4a*)&t[r][g * 16 + 8] = *(const u32x4a*)(src + 8);
  __syncthreads();
  union { u16 s[16]; u32x4 v[2]; } u;
#pragma unroll
  for (int e = 0; e < 16; ++e) u.s[e] = t[g * 16 + e][r];
  u16* dst = &vt[(size_t)((b * 16 + h) * 64 + r) * 2048 + s0 + g * 16];
  *(u32x4a*)dst = u.v[0];
  *(u32x4a*)(dst + 8) = u.v[1];
}

// ---------------- GEMM: C[M,N] = A[M,K]*BT[N,K]^T + bias ----------------
// 256x128 tile, BK=32, 512 threads (8 waves, 4M x 2N, 64x64 per wave).
// Ring of 4 LDS buffers (96 KiB), prefetch distance 3, counted vmcnt(6).
// Raw s_barrier + inline-asm waits (T3/T4); setprio around MFMA (T5).
// T2 swizzle both-sides (rule #21): pre-swizzled global source + swizzled
// ds_read; stage writes linear.
template <bool BF16_OUT>
__global__ __launch_bounds__(512, 2)
void gemm_bt(const u16* __restrict__ A, const u16* __restrict__ BT,
             const float* __restrict__ bias, void* __restrict__ Cv,
             int M, int N, int K) {
  constexpr int BK = 32;
  __shared__ __align__(16) u16 ring[4][12288];
  const int tid = threadIdx.x;
  const int wid = tid >> 6, lane = tid & 63;
  const int quad = lane >> 4, l16 = lane & 15;

  const int nbx = gridDim.x, nwg = nbx * gridDim.y;
  int bid = blockIdx.y * nbx + blockIdx.x;
  if ((nwg & 7) == 0) bid = (bid & 7) * (nwg >> 3) + (bid >> 3);
  const int tile_n = (bid % nbx) << 7;  // BN=128
  const int tile_m = (bid / nbx) << 8;  // BM=256

  const int wmR = (wid >> 1) << 6;
  const int wnR = (wid & 1) << 6;

  const int G0 = wid * 64 + lane;
  const int rA0 = G0 >> 2;
  const int sA0 = (((G0 & 3) ^ ((rA0 & 3) ^ ((rA0 >> 2) & 3)))) * 8;
  const int G1 = G0 + 512;
  const int rA1 = G1 >> 2;
  const int sA1 = (((G1 & 3) ^ ((rA1 & 3) ^ ((rA1 >> 2) & 3)))) * 8;
  const u16* const pA0 = A + (size_t)(tile_m + rA0) * K + sA0;
  const u16* const pA1 = A + (size_t)(tile_m + rA1) * K + sA1;
  const u16* const pB0 = BT + (size_t)(tile_n + rA0) * K + sA0;
  const int dst0 = wid * 512;
  const int dst1 = 4096 + wid * 512;
  const int dstB = 8192 + wid * 512;

  const int swl = (l16 & 3) ^ ((l16 >> 2) & 3);
  const int cA = (quad ^ swl) * 8;

  const int nk = K >> 5;
  f32x4 acc[4][4] = {};

  auto STAGE = [&](int kt) {
    u16* bp = ring[kt & 3];
    const size_t ko = (size_t)kt * BK;
    gload_lds16(pA0 + ko, bp + dst0);
    gload_lds16(pA1 + ko, bp + dst1);
    gload_lds16(pB0 + ko, bp + dstB);
  };

  STAGE(0);
  if (nk > 1) STAGE(1);
  if (nk > 2) STAGE(2);

  for (int kt = 0; kt < nk; ++kt) {
    asm volatile("s_waitcnt vmcnt(6)" ::: "memory");
    __builtin_amdgcn_sched_barrier(0);
    __builtin_amdgcn_s_barrier();
    __builtin_amdgcn_sched_barrier(0);
    if (kt + 3 < nk) STAGE(kt + 3);
    const u16* bp = ring[kt & 3];
    bf16x8 af[4], bfr[4];
#pragma unroll
    for (int i = 0; i < 4; ++i)
      af[i] = ld16(&bp[(wmR + i * 16 + l16) * BK + cA]);
#pragma unroll
    for (int j = 0; j < 4; ++j)
      bfr[j] = ld16(&bp[8192 + (wnR + j * 16 + l16) * BK + cA]);
    asm volatile("s_waitcnt lgkmcnt(0)" ::: "memory");
    __builtin_amdgcn_sched_barrier(0);
    __builtin_amdgcn_s_setprio(1);
#pragma unroll
    for (int i = 0; i < 4; ++i)
#pragma unroll
      for (int j = 0; j < 4; ++j) acc[i][j] = mfma16(af[i], bfr[j], acc[i][j]);
    __builtin_amdgcn_s_setprio(0);
  }

#pragma unroll
  for (int j = 0; j < 4; ++j) {
    const int cg = tile_n + wnR + j * 16 + l16;
    const float bv = bias[cg];
#pragma unroll
    for (int i = 0; i < 4; ++i) {
      const int rg = tile_m + wmR + i * 16 + quad * 4;
#pragma unroll
      for (int r = 0; r < 4; ++r) {
        const float v = acc[i][j][r] + bv;
        if constexpr (BF16_OUT)
          ((u16*)Cv)[(size_t)(rg + r) * N + cg] = f2bf(v);
        else
          ((float*)Cv)[(size_t)(rg + r) * N + cg] = v;
      }
    }
  }
}

// ---------------- causal flash attention (mfma32, QBLK=32/wave) ----------
// grid (16 h, 8 pair-slots, nb). Block y does 128-row q-tiles {15-y, y}:
// uniform 36 k-iterations. 512 blocks, 2/CU resident (launch_bounds(256,2)).
// Swapped QK via mfma_f32_32x32x16: S^T[k][q], q = lane&31 (32 q/wave), k =
// (reg&3)+8*(reg>>2)+4*hi per 32-k half. P-exchange to the PV B-layout
// (k = hi*8+e) is EXACTLY permlane32_swap on cvt_pk pairs: 16 cvt_pk +
// 8 permlane, zero shuffles/cndmask (verified word-by-word vs layouts).
// Scale folded into exp2 fma (raw-s defer threshold 8/SC); row-sum l done
// on the MFMA pipe via ones-row mfma into lacc (rescale applies naturally).
// K/V staged per block in double-buffered LDS (stage kt+1 at top of iter kt,
// drained by end-of-iter __syncthreads); both-sides XOR swizzle (rule #21):
// source col granule ^ (row&7), same XOR on ds_read -> conflict-free.
__global__ __launch_bounds__(256, 2)
void attn_fwd(const u16* __restrict__ qkv, const u16* __restrict__ vt,
              u16* __restrict__ aout) {
  const int h = blockIdx.x, b = blockIdx.z;
  const int tid = threadIdx.x, wid = tid >> 6, lane = tid & 63;
  const int l31 = lane & 31, hi = lane >> 5;
  __shared__ __align__(16) u16 lK[2][4096];  // [buf][64 k x 64 d]
  __shared__ __align__(16) u16 lV[2][4096];  // [buf][64 d x 64 k]

  // staging geometry: granule G -> row=G>>3, slot=G&7; source col pre-swizzled
  const int G0 = wid * 64 + lane, G1 = G0 + 256;
  const int r0 = G0 >> 3, c0 = ((G0 & 7) ^ (r0 & 7)) * 8;
  const int r1 = G1 >> 3, c1 = ((G1 & 7) ^ (r1 & 7)) * 8;
  const int db0 = wid * 512, db1 = 2048 + wid * 512;

  const u16* const kg = qkv + (size_t)(b * SEQ) * 3072 + 1024 + h * 64;
  const u16* const vg = vt + (size_t)((b * 16 + h) * 64) * 2048;

  constexpr float SC = 0.1803368801f;  // (1/8)*log2(e)
  constexpr float THR = 44.3614196f;   // 8 / SC (defer threshold on raw s)

  u32x4 onesu;
  onesu[0] = onesu[1] = onesu[2] = onesu[3] = 0x3F803F80u;  // bf16 1.0 x8
  const bf16x8 ones = __builtin_bit_cast(bf16x8, onesu);

  const int sx = l31 & 7;  // read-side row-XOR
  int cur = 0;

#pragma unroll 1
  for (int pass = 0; pass < 2; ++pass) {
    const int qt = pass ? (int)blockIdx.y : 15 - (int)blockIdx.y;
    const int q0w = qt * 128 + wid * 32;
    const int qrow = q0w + l31;
    bf16x8 qf[4];  // B-operand: Q[qrow][dblk*16 + hi*8 .. +7]
#pragma unroll
    for (int d = 0; d < 4; ++d)
      qf[d] = ld16(&qkv[(size_t)(b * SEQ + qrow) * 3072 + h * 64 + d * 16 + hi * 8]);
    f32x16 o0 = {}, o1 = {}, lacc = {};
    float m_r = -1e30f, ms = -1.8e29f;

    gload_lds16(kg + (size_t)r0 * 3072 + c0, &lK[cur][db0]);
    gload_lds16(kg + (size_t)r1 * 3072 + c1, &lK[cur][db1]);
    gload_lds16(vg + (size_t)r0 * 2048 + c0, &lV[cur][db0]);
    gload_lds16(vg + (size_t)r1 * 2048 + c1, &lV[cur][db1]);
    __syncthreads();

    const int last = 2 * qt + 1;
    for (int kt = 0; kt <= last; ++kt) {
      const int kb = kt * 64;
      if (kt < last) {  // stage next tile into the other buffer (async)
        const int kn = kb + 64;
        gload_lds16(kg + (size_t)(kn + r0) * 3072 + c0, &lK[cur ^ 1][db0]);
        gload_lds16(kg + (size_t)(kn + r1) * 3072 + c1, &lK[cur ^ 1][db1]);
        gload_lds16(vg + (size_t)r0 * 2048 + kn + c0, &lV[cur ^ 1][db0]);
        gload_lds16(vg + (size_t)r1 * 2048 + kn + c1, &lV[cur ^ 1][db1]);
      }
      if (kb <= q0w + 31) {  // wave-uniform: tile not fully masked
        const u16* const lKc = lK[cur];
        const u16* const lVc = lV[cur];
        // QK^T: S^T halves (k 0..31, 32..63)
        f32x16 s0 = {}, s1 = {};
#pragma unroll
        for (int d = 0; d < 4; ++d) {
          const bf16x8 kf = ld16(&lKc[l31 * 64 + (((d * 2 + hi) ^ sx)) * 8]);
          s0 = mfma32(kf, qf[d], s0);
        }
#pragma unroll
        for (int d = 0; d < 4; ++d) {
          const bf16x8 kf = ld16(&lKc[(32 + l31) * 64 + (((d * 2 + hi) ^ sx)) * 8]);
          s1 = mfma32(kf, qf[d], s1);
        }
        // V^T A-fragments, issued early (latency hides under softmax)
        bf16x8 vf[2][2][2];  // [kh][j][dh]
#pragma unroll
        for (int kh = 0; kh < 2; ++kh)
#pragma unroll
          for (int j = 0; j < 2; ++j)
#pragma unroll
            for (int dh = 0; dh < 2; ++dh)
              vf[kh][j][dh] = ld16(
                  &lVc[(dh * 32 + l31) * 64 + (((kh * 4 + j * 2 + hi) ^ sx)) * 8]);
        if (kb + 63 > q0w) {  // wave-uniform: diagonal masking needed
          const int rel = qrow - kb - 4 * hi;
#pragma unroll
          for (int i = 0; i < 16; ++i) {
            const int kc = (i & 3) + 8 * (i >> 2);
            if (kc > rel) s0[i] = -1e30f;
            if (kc + 32 > rel) s1[i] = -1e30f;
          }
        }
        // per-lane max over 32 (max3-fusable chain) + defer-max
        float pm = fmaxf(fmaxf(s0[0], s0[1]), s0[2]);
        pm = fmaxf(fmaxf(pm, s0[3]), s0[4]);
        pm = fmaxf(fmaxf(pm, s0[5]), s0[6]);
        pm = fmaxf(fmaxf(pm, s0[7]), s0[8]);
        pm = fmaxf(fmaxf(pm, s0[9]), s0[10]);
        pm = fmaxf(fmaxf(pm, s0[11]), s0[12]);
        pm = fmaxf(fmaxf(pm, s0[13]), s0[14]);
        pm = fmaxf(fmaxf(pm, s0[15]), s1[0]);
        pm = fmaxf(fmaxf(pm, s1[1]), s1[2]);
        pm = fmaxf(fmaxf(pm, s1[3]), s1[4]);
        pm = fmaxf(fmaxf(pm, s1[5]), s1[6]);
        pm = fmaxf(fmaxf(pm, s1[7]), s1[8]);
        pm = fmaxf(fmaxf(pm, s1[9]), s1[10]);
        pm = fmaxf(fmaxf(pm, s1[11]), s1[12]);
        pm = fmaxf(fmaxf(pm, s1[13]), s1[14]);
        pm = fmaxf(pm, s1[15]);
        if (__any(pm > m_r + THR)) {
          const float mm = fmaxf(pm, __shfl_xor(pm, 32));
          const float mn = fmaxf(m_r, mm);
          const float al = exp2f((m_r - mn) * SC);
#pragma unroll
          for (int i = 0; i < 16; ++i) {
            o0[i] *= al; o1[i] *= al; lacc[i] *= al;
          }
          m_r = mn;
          ms = mn * SC;
        }
        // p = 2^(s*SC - ms)  (bounded by 2^8)
#pragma unroll
        for (int i = 0; i < 16; ++i) {
          s0[i] = exp2f(fmaf(s0[i], SC, -ms));
          s1[i] = exp2f(fmaf(s1[i], SC, -ms));
        }
        // pack P -> PV B-fragments: cvt_pk pairs + permlane32_swap only
        u32 t0 = cvtpk(s0[0], s0[1]), t1 = cvtpk(s0[2], s0[3]);
        u32 t2 = cvtpk(s0[4], s0[5]), t3 = cvtpk(s0[6], s0[7]);
        u32 t4 = cvtpk(s0[8], s0[9]), t5 = cvtpk(s0[10], s0[11]);
        u32 t6 = cvtpk(s0[12], s0[13]), t7 = cvtpk(s0[14], s0[15]);
        plane32_swap(t0, t2); plane32_swap(t1, t3);
        plane32_swap(t4, t6); plane32_swap(t5, t7);
        u32x4 w00, w01;
        w00[0] = t0; w00[1] = t1; w00[2] = t2; w00[3] = t3;
        w01[0] = t4; w01[1] = t5; w01[2] = t6; w01[3] = t7;
        u32 u0 = cvtpk(s1[0], s1[1]), u1 = cvtpk(s1[2], s1[3]);
        u32 u2 = cvtpk(s1[4], s1[5]), u3 = cvtpk(s1[6], s1[7]);
        u32 u4 = cvtpk(s1[8], s1[9]), u5 = cvtpk(s1[10], s1[11]);
        u32 u6 = cvtpk(s1[12], s1[13]), u7 = cvtpk(s1[14], s1[15]);
        plane32_swap(u0, u2); plane32_swap(u1, u3);
        plane32_swap(u4, u6); plane32_swap(u5, u7);
        u32x4 w10, w11;
        w10[0] = u0; w10[1] = u1; w10[2] = u2; w10[3] = u3;
        w11[0] = u4; w11[1] = u5; w11[2] = u6; w11[3] = u7;
        const bf16x8 pb00 = __builtin_bit_cast(bf16x8, w00);
        const bf16x8 pb01 = __builtin_bit_cast(bf16x8, w01);
        const bf16x8 pb10 = __builtin_bit_cast(bf16x8, w10);
        const bf16x8 pb11 = __builtin_bit_cast(bf16x8, w11);
        // O^T += V^T * P^T ; l-sum on MFMA pipe via ones-row
        o0 = mfma32(vf[0][0][0], pb00, o0);
        o1 = mfma32(vf[0][0][1], pb00, o1);
        lacc = mfma32(ones, pb00, lacc);
        o0 = mfma32(vf[0][1][0], pb01, o0);
        o1 = mfma32(vf[0][1][1], pb01, o1);
        lacc = mfma32(ones, pb01, lacc);
        o0 = mfma32(vf[1][0][0], pb10, o0);
        o1 = mfma32(vf[1][0][1], pb10, o1);
        lacc = mfma32(ones, pb10, lacc);
        o0 = mfma32(vf[1][1][0], pb11, o0);
        o1 = mfma32(vf[1][1][1], pb11, o1);
        lacc = mfma32(ones, pb11, lacc);
      }
      __syncthreads();  // drains vmcnt (next tile staged) + WAR for buffers
      cur ^= 1;
    }
    // epilogue: o[dh][reg] = O^T[d = dh*32+(reg&3)+8*(reg>>2)+4*hi][q = l31]
    const float inv = 1.0f / lacc[0];
    u16* const orow = &aout[(size_t)(b * SEQ + qrow) * 1024 + h * 64];
#pragma unroll
    for (int t = 0; t < 4; ++t) {
      const int d0 = 8 * t + 4 * hi;
      uint2a wv;
      wv.x = cvtpk(o0[4 * t] * inv, o0[4 * t + 1] * inv);
      wv.y = cvtpk(o0[4 * t + 2] * inv, o0[4 * t + 3] * inv);
      *(uint2a*)&orow[d0] = wv;
      wv.x = cvtpk(o1[4 * t] * inv, o1[4 * t + 1] * inv);
      wv.y = cvtpk(o1[4 * t + 2] * inv, o1[4 * t + 3] * inv);
      *(uint2a*)&orow[32 + d0] = wv;
    }
  }
}

extern "C" void kernel_launch(void* const* d_in, const int* in_sizes, int n_in,
                              void* d_out, int out_size, void* d_ws, size_t ws_size,
                              hipStream_t stream) {
  const void* x     = d_in[0];
  const void* w_qkv = d_in[1];
  const void* b_qkv = d_in[2];
  const void* w_out = d_in[3];
  const void* b_out = d_in[4];
  float* out = (float*)d_out;  // reference output dtype is fp32

  // common prefix
  float* bqf   = (float*)d_ws;                      // [3072] fp32
  float* bof   = bqf + 3072;                        // [1024] fp32
  int*   flag  = (int*)(bof + 1024);                // [4]
  u16*   wqkvT = (u16*)(flag + 4);                  // [3072,1024]
  u16*   woutT = wqkvT + (size_t)3072 * 1024;       // [1024,1024]
  u16*   xb    = woutT + (size_t)1024 * 1024;       // [M,1024]

  detect_dtype<<<dim3(1), dim3(64), 0, stream>>>((const u16*)x, flag);
  cvt_bias<<<dim3(12), dim3(256), 0, stream>>>(b_qkv, bqf, 3072, flag);
  cvt_bias<<<dim3(4), dim3(256), 0, stream>>>(b_out, bof, 1024, flag);
  transpose_w<<<dim3(48, 16), dim3(256), 0, stream>>>(w_qkv, wqkvT, 1024, 3072, flag);
  transpose_w<<<dim3(16, 16), dim3(256), 0, stream>>>(w_out, woutT, 1024, 1024, flag);

  // full-batch path needs 92,291,088 B of ws; fall back to per-batch otherwise.
  const size_t FULL_WS = 92291088;  // constant across calls -> graph-safe branch
  if (ws_size >= FULL_WS) {
    u16* qkv = xb  + (size_t)8192 * 1024;           // [8192,3072]
    u16* vt  = qkv + (size_t)8192 * 3072;           // [64,64,2048]
    cvt_x<<<dim3(8192), dim3(256), 0, stream>>>(x, xb, flag, 0);
    gemm_bt<true ><<<dim3(24, 32), dim3(512), 0, stream>>>(xb, wqkvT, bqf, qkv,
                                                           8192, 3072, 1024);
    transpose_v<<<dim3(16, 32, 4), dim3(256), 0, stream>>>(qkv, vt);
    attn_fwd<<<dim3(16, 8, 4), dim3(256), 0, stream>>>(qkv, vt, xb);
    gemm_bt<false><<<dim3(8, 32), dim3(512), 0, stream>>>(xb, woutT, bof, out,
                                                          8192, 1024, 1024);
  } else {
    u16* qkvb = xb   + (size_t)2048 * 1024;         // [2048,3072]
    u16* vtb  = qkvb + (size_t)2048 * 3072;         // [16,64,2048]
    for (int b = 0; b < 4; ++b) {
      const size_t eoff4 = (size_t)b * 2048 * 1024 / 4;
      cvt_x<<<dim3(2048), dim3(256), 0, stream>>>(x, xb, flag, eoff4);
      gemm_bt<true ><<<dim3(24, 8), dim3(512), 0, stream>>>(xb, wqkvT, bqf, qkvb,
                                                            2048, 3072, 1024);
      transpose_v<<<dim3(16, 32, 1), dim3(256), 0, stream>>>(qkvb, vtb);
      attn_fwd<<<dim3(16, 8, 1), dim3(256), 0, stream>>>(qkvb, vtb, xb);
      gemm_bt<false><<<dim3(8, 8), dim3(512), 0, stream>>>(
          xb, woutT, bof, out + (size_t)b * 2048 * 1024, 2048, 1024, 1024);
    }
  }
}

// Round 5
// 295.457 us; speedup vs baseline: 1.8446x; 1.0124x over previous
//
#include <hip/hip_runtime.h>

typedef unsigned short u16;
typedef unsigned int u32;
using f32x4 = __attribute__((ext_vector_type(4))) float;
using f32x16 = __attribute__((ext_vector_type(16))) float;
using u32x4 = __attribute__((ext_vector_type(4))) u32;
typedef u32x4 __attribute__((may_alias)) u32x4a;  // TBAA-safe 16B vector
typedef uint2 __attribute__((may_alias)) uint2a;  // TBAA-safe 8B vector
using bf16x8 = __attribute__((ext_vector_type(8))) __bf16;

#define SEQ 2048  // per batch

// fp32 -> bf16 round-to-nearest-even
__device__ __forceinline__ u16 f2bf(float f) {
  union { float f; u32 u; } c; c.f = f;
  return (u16)((c.u + 0x7fffu + ((c.u >> 16) & 1u)) >> 16);
}
__device__ __forceinline__ float bf2f(u16 h) {
  union { u32 u; float f; } c; c.u = ((u32)h) << 16;
  return c.f;
}
__device__ __forceinline__ bf16x8 ld16(const u16* p) {
  return __builtin_bit_cast(bf16x8, *(const u32x4a*)p);
}
__device__ __forceinline__ f32x4 mfma16(bf16x8 a, bf16x8 b, f32x4 c) {
  return __builtin_amdgcn_mfma_f32_16x16x32_bf16(a, b, c, 0, 0, 0);
}
__device__ __forceinline__ f32x16 mfma32(bf16x8 a, bf16x8 b, f32x16 c) {
  return __builtin_amdgcn_mfma_f32_32x32x16_bf16(a, b, c, 0, 0, 0);
}
// async global->LDS, 16B/lane; LDS dest = wave-uniform base + lane*16
__device__ __forceinline__ void gload_lds16(const u16* g, u16* l) {
  __builtin_amdgcn_global_load_lds(
      (const __attribute__((address_space(1))) void*)g,
      (__attribute__((address_space(3))) void*)l, 16, 0, 0);
}
// pack 2 fp32 -> 1 u32 of 2 bf16 (RNE); no builtin on gfx950
__device__ __forceinline__ u32 cvtpk(float lo, float hi) {
  u32 r;
  asm("v_cvt_pk_bf16_f32 %0, %1, %2" : "=v"(r) : "v"(lo), "v"(hi));
  return r;
}
// new_a = [a.lanes0-31 | b.lanes0-31], new_b = [a.lanes32-63 | b.lanes32-63]
__device__ __forceinline__ void plane32_swap(u32& a, u32& b) {
  asm("v_permlane32_swap_b32 %0, %1" : "+v"(a), "+v"(b));
}

// ---------------- input dtype detection ----------------
__global__ void detect_dtype(const u16* __restrict__ x, int* __restrict__ flag) {
  if (threadIdx.x == 0) {
    int cnt = 0;
    for (int i = 0; i < 32; ++i) {
      const int e = (x[2 * i] >> 7) & 0xFF;
      cnt += (e >= 100 && e <= 140) ? 1 : 0;
    }
    *flag = (cnt >= 20) ? 1 : 0;  // 1 = inputs are bf16
  }
}

// ---------------- prep kernels ----------------

__global__ __launch_bounds__(256)
void cvt_x(const void* __restrict__ in, u16* __restrict__ out,
           const int* __restrict__ flag, size_t eoff4) {
  const size_t i = (size_t)blockIdx.x * 256 + threadIdx.x;
  if (*flag) {
    ((uint2*)out)[i] = ((const uint2*)in)[eoff4 + i];
  } else {
    const float4 v = ((const float4*)in)[eoff4 + i];
    uint2 ov;
    ov.x = (u32)f2bf(v.x) | ((u32)f2bf(v.y) << 16);
    ov.y = (u32)f2bf(v.z) | ((u32)f2bf(v.w) << 16);
    ((uint2*)out)[i] = ov;
  }
}

__global__ __launch_bounds__(256)
void cvt_bias(const void* __restrict__ in, float* __restrict__ out, int n,
              const int* __restrict__ flag) {
  const int i = blockIdx.x * 256 + threadIdx.x;
  if (i >= n) return;
  out[i] = (*flag) ? bf2f(((const u16*)in)[i]) : ((const float*)in)[i];
}

// in [K,N] (fp32 or bf16) -> out bf16 [N,K]. 64x64 tiles via LDS.
__global__ __launch_bounds__(256)
void transpose_w(const void* __restrict__ in, u16* __restrict__ out, int K, int N,
                 const int* __restrict__ flag) {
  __shared__ float t[64][65];
  const int tid = threadIdx.x;
  const int r = tid >> 4, c4 = tid & 15;
  const int n0 = blockIdx.x << 6, k0 = blockIdx.y << 6;
  const int fl = *flag;
#pragma unroll
  for (int i = 0; i < 4; ++i) {
    const int kk = r + i * 16;
    const size_t base = (size_t)(k0 + kk) * N + n0 + c4 * 4;
    if (fl) {
      const uint2 raw = *(const uint2*)((const u16*)in + base);
      t[kk][c4 * 4 + 0] = bf2f((u16)(raw.x & 0xFFFF));
      t[kk][c4 * 4 + 1] = bf2f((u16)(raw.x >> 16));
      t[kk][c4 * 4 + 2] = bf2f((u16)(raw.y & 0xFFFF));
      t[kk][c4 * 4 + 3] = bf2f((u16)(raw.y >> 16));
    } else {
      const float4 v = *(const float4*)((const float*)in + base);
      t[kk][c4 * 4 + 0] = v.x; t[kk][c4 * 4 + 1] = v.y;
      t[kk][c4 * 4 + 2] = v.z; t[kk][c4 * 4 + 3] = v.w;
    }
  }
  __syncthreads();
#pragma unroll
  for (int i = 0; i < 4; ++i) {
    const int nn = r + i * 16;
    uint2 ov;
    ov.x = (u32)f2bf(t[c4 * 4 + 0][nn]) | ((u32)f2bf(t[c4 * 4 + 1][nn]) << 16);
    ov.y = (u32)f2bf(t[c4 * 4 + 2][nn]) | ((u32)f2bf(t[c4 * 4 + 3][nn]) << 16);
    *(uint2*)&out[(size_t)(n0 + nn) * K + k0 + c4 * 4] = ov;
  }
}

// qkv bf16 [nb*2048, 3072] (V cols 2048..3071) -> vt [nb*16][d=64][s=2048]
__global__ __launch_bounds__(256)
void transpose_v(const u16* __restrict__ qkv, u16* __restrict__ vt) {
  __shared__ __align__(16) u16 t[64][72];
  const int h = blockIdx.x, s0 = blockIdx.y << 6, b = blockIdx.z;
  const int tid = threadIdx.x;
  const int r = tid >> 2, g = tid & 3;
  const u16* src = &qkv[(size_t)(b * SEQ + s0 + r) * 3072 + 2048 + h * 64 + g * 16];
  *(u32x4a*)&t[r][g * 16]     = *(const u32x4a*)src;
  *(u32x4a*)&t[r][g * 16 + 8] = *(const u32x4a*)(src + 8);
  __syncthreads();
  union { u16 s[16]; u32x4 v[2]; } u;
#pragma unroll
  for (int e = 0; e < 16; ++e) u.s[e] = t[g * 16 + e][r];
  u16* dst = &vt[(size_t)((b * 16 + h) * 64 + r) * 2048 + s0 + g * 16];
  *(u32x4a*)dst = u.v[0];
  *(u32x4a*)(dst + 8) = u.v[1];
}

// ---------------- GEMM: C[M,N] = A[M,K]*BT[N,K]^T + bias ----------------
// 256x128 tile, BK=32, 512 threads (8 waves, 4M x 2N, 64x64 per wave).
// Ring of 4 LDS buffers (96 KiB), prefetch distance 3, counted vmcnt(6).
// Raw s_barrier + inline-asm waits (T3/T4); setprio around MFMA (T5).
// T2 swizzle both-sides (rule #21): pre-swizzled global source + swizzled
// ds_read; stage writes linear.
template <bool BF16_OUT>
__global__ __launch_bounds__(512, 2)
void gemm_bt(const u16* __restrict__ A, const u16* __restrict__ BT,
             const float* __restrict__ bias, void* __restrict__ Cv,
             int M, int N, int K) {
  constexpr int BK = 32;
  __shared__ __align__(16) u16 ring[4][12288];
  const int tid = threadIdx.x;
  const int wid = tid >> 6, lane = tid & 63;
  const int quad = lane >> 4, l16 = lane & 15;

  const int nbx = gridDim.x, nwg = nbx * gridDim.y;
  int bid = blockIdx.y * nbx + blockIdx.x;
  if ((nwg & 7) == 0) bid = (bid & 7) * (nwg >> 3) + (bid >> 3);
  const int tile_n = (bid % nbx) << 7;  // BN=128
  const int tile_m = (bid / nbx) << 8;  // BM=256

  const int wmR = (wid >> 1) << 6;
  const int wnR = (wid & 1) << 6;

  const int G0 = wid * 64 + lane;
  const int rA0 = G0 >> 2;
  const int sA0 = (((G0 & 3) ^ ((rA0 & 3) ^ ((rA0 >> 2) & 3)))) * 8;
  const int G1 = G0 + 512;
  const int rA1 = G1 >> 2;
  const int sA1 = (((G1 & 3) ^ ((rA1 & 3) ^ ((rA1 >> 2) & 3)))) * 8;
  const u16* const pA0 = A + (size_t)(tile_m + rA0) * K + sA0;
  const u16* const pA1 = A + (size_t)(tile_m + rA1) * K + sA1;
  const u16* const pB0 = BT + (size_t)(tile_n + rA0) * K + sA0;
  const int dst0 = wid * 512;
  const int dst1 = 4096 + wid * 512;
  const int dstB = 8192 + wid * 512;

  const int swl = (l16 & 3) ^ ((l16 >> 2) & 3);
  const int cA = (quad ^ swl) * 8;

  const int nk = K >> 5;
  f32x4 acc[4][4] = {};

  auto STAGE = [&](int kt) {
    u16* bp = ring[kt & 3];
    const size_t ko = (size_t)kt * BK;
    gload_lds16(pA0 + ko, bp + dst0);
    gload_lds16(pA1 + ko, bp + dst1);
    gload_lds16(pB0 + ko, bp + dstB);
  };

  STAGE(0);
  if (nk > 1) STAGE(1);
  if (nk > 2) STAGE(2);

  for (int kt = 0; kt < nk; ++kt) {
    asm volatile("s_waitcnt vmcnt(6)" ::: "memory");
    __builtin_amdgcn_sched_barrier(0);
    __builtin_amdgcn_s_barrier();
    __builtin_amdgcn_sched_barrier(0);
    if (kt + 3 < nk) STAGE(kt + 3);
    const u16* bp = ring[kt & 3];
    bf16x8 af[4], bfr[4];
#pragma unroll
    for (int i = 0; i < 4; ++i)
      af[i] = ld16(&bp[(wmR + i * 16 + l16) * BK + cA]);
#pragma unroll
    for (int j = 0; j < 4; ++j)
      bfr[j] = ld16(&bp[8192 + (wnR + j * 16 + l16) * BK + cA]);
    asm volatile("s_waitcnt lgkmcnt(0)" ::: "memory");
    __builtin_amdgcn_sched_barrier(0);
    __builtin_amdgcn_s_setprio(1);
#pragma unroll
    for (int i = 0; i < 4; ++i)
#pragma unroll
      for (int j = 0; j < 4; ++j) acc[i][j] = mfma16(af[i], bfr[j], acc[i][j]);
    __builtin_amdgcn_s_setprio(0);
  }

#pragma unroll
  for (int j = 0; j < 4; ++j) {
    const int cg = tile_n + wnR + j * 16 + l16;
    const float bv = bias[cg];
#pragma unroll
    for (int i = 0; i < 4; ++i) {
      const int rg = tile_m + wmR + i * 16 + quad * 4;
#pragma unroll
      for (int r = 0; r < 4; ++r) {
        const float v = acc[i][j][r] + bv;
        if constexpr (BF16_OUT)
          ((u16*)Cv)[(size_t)(rg + r) * N + cg] = f2bf(v);
        else
          ((float*)Cv)[(size_t)(rg + r) * N + cg] = v;
      }
    }
  }
}

// ---------------- causal flash attention (mfma32, ring-4 pipeline) -------
// grid (16 h, 8 pair-slots, nb). Block y does 128-row q-tiles {15-y, y}:
// uniform iteration totals. 512 blocks, 2/CU. Grid id = h + 16y + 128b ->
// id%8 = h%8: all y-blocks of one (b,h) share an XCD -> K/V L2-resident
// (8 groups x 512 KB = 4 MB/XCD).
// NEW: ring of 4 K/V LDS buffers (64 KB), prefetch distance 3, counted
// vmcnt (8 steady / 4 / 0 at tail; never 0 mid-loop) + raw s_barrier +
// sched_barrier fences -- same proven ordering as gemm_bt: wait(kt) ->
// barrier -> stage(kt+3) -> compute(kt). Kills the per-iter vmcnt(0)
// drain that exposed the full L2/L3 round trip (measured ~6K cyc/iter).
// Compute section identical to round 4 (refcheck-proven): swapped 32x32
// QK (S^T), in-register P via cvt_pk+permlane32_swap, defer-max (THR=8
// base-2), l-sum on MFMA pipe via ones-row, setprio around MFMA clusters.
__global__ __launch_bounds__(256, 2)
void attn_fwd(const u16* __restrict__ qkv, const u16* __restrict__ vt,
              u16* __restrict__ aout) {
  const int h = blockIdx.x, b = blockIdx.z;
  const int tid = threadIdx.x, wid = tid >> 6, lane = tid & 63;
  const int l31 = lane & 31, hi = lane >> 5;
  __shared__ __align__(16) u16 ring[4][8192];  // [buf][K:0..4095 | V:4096..]

  // staging geometry: granule G -> row=G>>3, slot=G&7; source col pre-swizzled
  const int G0 = wid * 64 + lane, G1 = G0 + 256;
  const int r0 = G0 >> 3, c0 = ((G0 & 7) ^ (r0 & 7)) * 8;
  const int r1 = G1 >> 3, c1 = ((G1 & 7) ^ (r1 & 7)) * 8;
  const int db0 = wid * 512, db1 = 2048 + wid * 512;

  const u16* const kg = qkv + (size_t)(b * SEQ) * 3072 + 1024 + h * 64;
  const u16* const vg = vt + (size_t)((b * 16 + h) * 64) * 2048;

  constexpr float SC = 0.1803368801f;  // (1/8)*log2(e)
  constexpr float THR = 44.3614196f;   // 8 / SC (defer threshold on raw s)

  u32x4 onesu;
  onesu[0] = onesu[1] = onesu[2] = onesu[3] = 0x3F803F80u;  // bf16 1.0 x8
  const bf16x8 ones = __builtin_bit_cast(bf16x8, onesu);

  const int sx = l31 & 7;  // read-side row-XOR

  auto STAGE = [&](int kt) {
    u16* bp = ring[kt & 3];
    const int kb = kt * 64;
    gload_lds16(kg + (size_t)(kb + r0) * 3072 + c0, bp + db0);
    gload_lds16(kg + (size_t)(kb + r1) * 3072 + c1, bp + db1);
    gload_lds16(vg + (size_t)r0 * 2048 + kb + c0, bp + 4096 + db0);
    gload_lds16(vg + (size_t)r1 * 2048 + kb + c1, bp + 4096 + db1);
  };

#pragma unroll 1
  for (int pass = 0; pass < 2; ++pass) {
    const int qt = pass ? (int)blockIdx.y : 15 - (int)blockIdx.y;
    const int q0w = qt * 128 + wid * 32;
    const int qrow = q0w + l31;
    bf16x8 qf[4];  // B-operand: Q[qrow][dblk*16 + hi*8 .. +7]
#pragma unroll
    for (int d = 0; d < 4; ++d)
      qf[d] = ld16(&qkv[(size_t)(b * SEQ + qrow) * 3072 + h * 64 + d * 16 + hi * 8]);
    f32x16 o0 = {}, o1 = {}, lacc = {};
    float m_r = -1e30f, ms = -1.8e29f;

    const int last = 2 * qt + 1;
    __syncthreads();  // buffer handoff across passes (drains everything)
    STAGE(0);
    if (last >= 1) STAGE(1);
    if (last >= 2) STAGE(2);

#pragma unroll 1
    for (int kt = 0; kt <= last; ++kt) {
      // counted wait: stage(kt) retired (in-order retirement), deeper
      // prefetches stay in flight. 4 loads per stage.
      const int rem = last - kt;
      if (rem >= 2)      asm volatile("s_waitcnt vmcnt(8)" ::: "memory");
      else if (rem == 1) asm volatile("s_waitcnt vmcnt(4)" ::: "memory");
      else               asm volatile("s_waitcnt vmcnt(0)" ::: "memory");
      __builtin_amdgcn_sched_barrier(0);
      __builtin_amdgcn_s_barrier();  // all waves' stage(kt) complete; all
                                     // reads of buf[(kt-1)&3] finished
      __builtin_amdgcn_sched_barrier(0);
      if (kt + 3 <= last) STAGE(kt + 3);  // writes buf[(kt-1)&3]
      const int kb = kt * 64;
      if (kb <= q0w + 31) {  // wave-uniform: tile not fully masked
        const u16* const lKc = ring[kt & 3];
        const u16* const lVc = ring[kt & 3] + 4096;
        // QK^T: S^T halves (k 0..31, 32..63)
        f32x16 s0 = {}, s1 = {};
        bf16x8 kf0[4], kf1[4];
#pragma unroll
        for (int d = 0; d < 4; ++d) {
          kf0[d] = ld16(&lKc[l31 * 64 + (((d * 2 + hi) ^ sx)) * 8]);
          kf1[d] = ld16(&lKc[(32 + l31) * 64 + (((d * 2 + hi) ^ sx)) * 8]);
        }
        __builtin_amdgcn_s_setprio(1);
#pragma unroll
        for (int d = 0; d < 4; ++d) s0 = mfma32(kf0[d], qf[d], s0);
#pragma unroll
        for (int d = 0; d < 4; ++d) s1 = mfma32(kf1[d], qf[d], s1);
        __builtin_amdgcn_s_setprio(0);
        // V^T A-fragments, issued early (latency hides under softmax)
        bf16x8 vf[2][2][2];  // [kh][j][dh]
#pragma unroll
        for (int kh = 0; kh < 2; ++kh)
#pragma unroll
          for (int j = 0; j < 2; ++j)
#pragma unroll
            for (int dh = 0; dh < 2; ++dh)
              vf[kh][j][dh] = ld16(
                  &lVc[(dh * 32 + l31) * 64 + (((kh * 4 + j * 2 + hi) ^ sx)) * 8]);
        if (kb + 63 > q0w) {  // wave-uniform: diagonal masking needed
          const int rel = qrow - kb - 4 * hi;
#pragma unroll
          for (int i = 0; i < 16; ++i) {
            const int kc = (i & 3) + 8 * (i >> 2);
            if (kc > rel) s0[i] = -1e30f;
            if (kc + 32 > rel) s1[i] = -1e30f;
          }
        }
        // per-lane max over 32 (max3-fusable chain) + defer-max
        float pm = fmaxf(fmaxf(s0[0], s0[1]), s0[2]);
        pm = fmaxf(fmaxf(pm, s0[3]), s0[4]);
        pm = fmaxf(fmaxf(pm, s0[5]), s0[6]);
        pm = fmaxf(fmaxf(pm, s0[7]), s0[8]);
        pm = fmaxf(fmaxf(pm, s0[9]), s0[10]);
        pm = fmaxf(fmaxf(pm, s0[11]), s0[12]);
        pm = fmaxf(fmaxf(pm, s0[13]), s0[14]);
        pm = fmaxf(fmaxf(pm, s0[15]), s1[0]);
        pm = fmaxf(fmaxf(pm, s1[1]), s1[2]);
        pm = fmaxf(fmaxf(pm, s1[3]), s1[4]);
        pm = fmaxf(fmaxf(pm, s1[5]), s1[6]);
        pm = fmaxf(fmaxf(pm, s1[7]), s1[8]);
        pm = fmaxf(fmaxf(pm, s1[9]), s1[10]);
        pm = fmaxf(fmaxf(pm, s1[11]), s1[12]);
        pm = fmaxf(fmaxf(pm, s1[13]), s1[14]);
        pm = fmaxf(pm, s1[15]);
        if (__any(pm > m_r + THR)) {
          const float mm = fmaxf(pm, __shfl_xor(pm, 32));
          const float mn = fmaxf(m_r, mm);
          const float al = exp2f((m_r - mn) * SC);
#pragma unroll
          for (int i = 0; i < 16; ++i) {
            o0[i] *= al; o1[i] *= al; lacc[i] *= al;
          }
          m_r = mn;
          ms = mn * SC;
        }
        // p = 2^(s*SC - ms)  (bounded by 2^8)
#pragma unroll
        for (int i = 0; i < 16; ++i) {
          s0[i] = exp2f(fmaf(s0[i], SC, -ms));
          s1[i] = exp2f(fmaf(s1[i], SC, -ms));
        }
        // pack P -> PV B-fragments: cvt_pk pairs + permlane32_swap only
        u32 t0 = cvtpk(s0[0], s0[1]), t1 = cvtpk(s0[2], s0[3]);
        u32 t2 = cvtpk(s0[4], s0[5]), t3 = cvtpk(s0[6], s0[7]);
        u32 t4 = cvtpk(s0[8], s0[9]), t5 = cvtpk(s0[10], s0[11]);
        u32 t6 = cvtpk(s0[12], s0[13]), t7 = cvtpk(s0[14], s0[15]);
        plane32_swap(t0, t2); plane32_swap(t1, t3);
        plane32_swap(t4, t6); plane32_swap(t5, t7);
        u32x4 w00, w01;
        w00[0] = t0; w00[1] = t1; w00[2] = t2; w00[3] = t3;
        w01[0] = t4; w01[1] = t5; w01[2] = t6; w01[3] = t7;
        u32 u0 = cvtpk(s1[0], s1[1]), u1 = cvtpk(s1[2], s1[3]);
        u32 u2 = cvtpk(s1[4], s1[5]), u3 = cvtpk(s1[6], s1[7]);
        u32 u4 = cvtpk(s1[8], s1[9]), u5 = cvtpk(s1[10], s1[11]);
        u32 u6 = cvtpk(s1[12], s1[13]), u7 = cvtpk(s1[14], s1[15]);
        plane32_swap(u0, u2); plane32_swap(u1, u3);
        plane32_swap(u4, u6); plane32_swap(u5, u7);
        u32x4 w10, w11;
        w10[0] = u0; w10[1] = u1; w10[2] = u2; w10[3] = u3;
        w11[0] = u4; w11[1] = u5; w11[2] = u6; w11[3] = u7;
        const bf16x8 pb00 = __builtin_bit_cast(bf16x8, w00);
        const bf16x8 pb01 = __builtin_bit_cast(bf16x8, w01);
        const bf16x8 pb10 = __builtin_bit_cast(bf16x8, w10);
        const bf16x8 pb11 = __builtin_bit_cast(bf16x8, w11);
        // O^T += V^T * P^T ; l-sum on MFMA pipe via ones-row
        __builtin_amdgcn_s_setprio(1);
        o0 = mfma32(vf[0][0][0], pb00, o0);
        o1 = mfma32(vf[0][0][1], pb00, o1);
        lacc = mfma32(ones, pb00, lacc);
        o0 = mfma32(vf[0][1][0], pb01, o0);
        o1 = mfma32(vf[0][1][1], pb01, o1);
        lacc = mfma32(ones, pb01, lacc);
        o0 = mfma32(vf[1][0][0], pb10, o0);
        o1 = mfma32(vf[1][0][1], pb10, o1);
        lacc = mfma32(ones, pb10, lacc);
        o0 = mfma32(vf[1][1][0], pb11, o0);
        o1 = mfma32(vf[1][1][1], pb11, o1);
        lacc = mfma32(ones, pb11, lacc);
        __builtin_amdgcn_s_setprio(0);
      }
    }
    // epilogue: o[dh][reg] = O^T[d = dh*32+(reg&3)+8*(reg>>2)+4*hi][q = l31]
    const float inv = 1.0f / lacc[0];
    u16* const orow = &aout[(size_t)(b * SEQ + qrow) * 1024 + h * 64];
#pragma unroll
    for (int t = 0; t < 4; ++t) {
      const int d0 = 8 * t + 4 * hi;
      uint2a wv;
      wv.x = cvtpk(o0[4 * t] * inv, o0[4 * t + 1] * inv);
      wv.y = cvtpk(o0[4 * t + 2] * inv, o0[4 * t + 3] * inv);
      *(uint2a*)&orow[d0] = wv;
      wv.x = cvtpk(o1[4 * t] * inv, o1[4 * t + 1] * inv);
      wv.y = cvtpk(o1[4 * t + 2] * inv, o1[4 * t + 3] * inv);
      *(uint2a*)&orow[32 + d0] = wv;
    }
  }
}

extern "C" void kernel_launch(void* const* d_in, const int* in_sizes, int n_in,
                              void* d_out, int out_size, void* d_ws, size_t ws_size,
                              hipStream_t stream) {
  const void* x     = d_in[0];
  const void* w_qkv = d_in[1];
  const void* b_qkv = d_in[2];
  const void* w_out = d_in[3];
  const void* b_out = d_in[4];
  float* out = (float*)d_out;  // reference output dtype is fp32

  // common prefix
  float* bqf   = (float*)d_ws;                      // [3072] fp32
  float* bof   = bqf + 3072;                        // [1024] fp32
  int*   flag  = (int*)(bof + 1024);                // [4]
  u16*   wqkvT = (u16*)(flag + 4);                  // [3072,1024]
  u16*   woutT = wqkvT + (size_t)3072 * 1024;       // [1024,1024]
  u16*   xb    = woutT + (size_t)1024 * 1024;       // [M,1024]

  detect_dtype<<<dim3(1), dim3(64), 0, stream>>>((const u16*)x, flag);
  cvt_bias<<<dim3(12), dim3(256), 0, stream>>>(b_qkv, bqf, 3072, flag);
  cvt_bias<<<dim3(4), dim3(256), 0, stream>>>(b_out, bof, 1024, flag);
  transpose_w<<<dim3(48, 16), dim3(256), 0, stream>>>(w_qkv, wqkvT, 1024, 3072, flag);
  transpose_w<<<dim3(16, 16), dim3(256), 0, stream>>>(w_out, woutT, 1024, 1024, flag);

  // full-batch path needs 92,291,088 B of ws; fall back to per-batch otherwise.
  const size_t FULL_WS = 92291088;  // constant across calls -> graph-safe branch
  if (ws_size >= FULL_WS) {
    u16* qkv = xb  + (size_t)8192 * 1024;           // [8192,3072]
    u16* vt  = qkv + (size_t)8192 * 3072;           // [64,64,2048]
    cvt_x<<<dim3(8192), dim3(256), 0, stream>>>(x, xb, flag, 0);
    gemm_bt<true ><<<dim3(24, 32), dim3(512), 0, stream>>>(xb, wqkvT, bqf, qkv,
                                                           8192, 3072, 1024);
    transpose_v<<<dim3(16, 32, 4), dim3(256), 0, stream>>>(qkv, vt);
    attn_fwd<<<dim3(16, 8, 4), dim3(256), 0, stream>>>(qkv, vt, xb);
    gemm_bt<false><<<dim3(8, 32), dim3(512), 0, stream>>>(xb, woutT, bof, out,
                                                          8192, 1024, 1024);
  } else {
    u16* qkvb = xb   + (size_t)2048 * 1024;         // [2048,3072]
    u16* vtb  = qkvb + (size_t)2048 * 3072;         // [16,64,2048]
    for (int b = 0; b < 4; ++b) {
      const size_t eoff4 = (size_t)b * 2048 * 1024 / 4;
      cvt_x<<<dim3(2048), dim3(256), 0, stream>>>(x, xb, flag, eoff4);
      gemm_bt<true ><<<dim3(24, 8), dim3(512), 0, stream>>>(xb, wqkvT, bqf, qkvb,
                                                            2048, 3072, 1024);
      transpose_v<<<dim3(16, 32, 1), dim3(256), 0, stream>>>(qkvb, vtb);
      attn_fwd<<<dim3(16, 8, 1), dim3(256), 0, stream>>>(qkvb, vtb, xb);
      gemm_bt<false><<<dim3(8, 8), dim3(512), 0, stream>>>(
          xb, woutT, bof, out + (size_t)b * 2048 * 1024, 2048, 1024, 1024);
    }
  }
}